// Round 11
// baseline (3262.790 us; speedup 1.0000x reference)
//
#include <hip/hip_runtime.h>
#include <math.h>

#define BATCH 8
#define NPTS 8192
#define CFEAT 64
#define NC 2048           // S centers
#define KNN 32
#define NSCOL (NC*KNN)    // 65536 columns per batch
#define R2 0.0625f        // radius^2
#define GN_EPS 1e-5f
#define SBINS 32          // stat partial bins (cuts atomic contention 32x)

// ---- workspace layout (bytes) ----
#define OFF_CIDX   0ull
#define OFF_NIDX   65536ull
#define OFF_CENT   2162688ull
#define OFF_STATSP 2359296ull            // 3 layers x 32 bins x 128 fl = 49152 B
#define OFF_STATSF 2408448ull            // 3 x 128 fl = 1536 B
#define OFF_WT     2410496ull            // 16576 fl = 66304 B
#define OFF_XALL   4194304ull            // 17,825,792 B
#define OFF_Y      23068672ull           // 134,217,728 B
#define WS_NEEDED  (OFF_Y + 8ull*64*NSCOL*4ull)   // 150 MiB

static __device__ __forceinline__ unsigned f2bf(float f) {
    unsigned u = __float_as_uint(f);
    return (u + 0x7fffu + ((u >> 16) & 1u)) >> 16;   // RNE, finite inputs
}

// ---- fused u64-key DPP max step: all-VALU, no readlane, no SALU ----
// partner = dpp(hi,lo); if (partner > mine) take partner.
// bound_ctrl=false + old=self: invalid-src lanes compare self>self -> keep.
template<int CTRL>
static __device__ __forceinline__ void dppmax64(unsigned& hi, unsigned& lo) {
    unsigned phi = (unsigned)__builtin_amdgcn_update_dpp((int)hi, (int)hi,
                                                         CTRL, 0xf, 0xf, false);
    unsigned plo = (unsigned)__builtin_amdgcn_update_dpp((int)lo, (int)lo,
                                                         CTRL, 0xf, 0xf, false);
    unsigned long long mine   = ((unsigned long long)hi  << 32) | lo;
    unsigned long long theirs = ((unsigned long long)phi << 32) | plo;
    if (theirs > mine) { hi = phi; lo = plo; }
}

// =====================================================================
// prep: zero stat partials/finals; transpose weights to [i][o] layout.
// =====================================================================
__global__ void prep_kernel(const float* __restrict__ w0, const float* __restrict__ w1,
                            const float* __restrict__ w2, float* __restrict__ statsP,
                            float* __restrict__ statsF, float* __restrict__ wt)
{
    const int t = blockIdx.x * 256 + threadIdx.x;
    if (t < 3 * SBINS * 128) statsP[t] = 0.f;
    if (t < 384) statsF[t] = 0.f;
    if (t < 64 * 67) { int o = t / 67, i = t - o * 67; wt[i * 64 + o] = w0[t]; }
    if (t < 64 * 64) { int o = t >> 6, i = t & 63;     wt[4288 + i * 64 + o] = w1[t]; }
    if (t < 128 * 64){ int o = t >> 6, i = t & 63;     wt[8384 + i * 128 + o] = w2[t]; }
}

// =====================================================================
__global__ void reduce_stats(const float* __restrict__ statsPL, float* __restrict__ statsFL)
{
    const int t = threadIdx.x;
    if (t < 128) {
        float s = 0.f;
#pragma unroll
        for (int bin = 0; bin < SBINS; ++bin) s += statsPL[bin * 128 + t];
        statsFL[t] = s;
    }
}

// =====================================================================
// build point-major input records: xall[b][p][0..2]=coords, [3..66]=feats,
// [67]=pad (272 B record, float4-aligned). float4-packed stores.
// =====================================================================
__global__ __launch_bounds__(256) void build_xall(const float* __restrict__ coords,
                                                  const float* __restrict__ feats,
                                                  float* __restrict__ xall)
{
    const int tid = blockIdx.x * 256 + threadIdx.x;   // b*NPTS + p
    const int b = tid >> 13, p = tid & (NPTS - 1);
    const float* cb = coords + (size_t)b * 3 * NPTS;
    const float* fb = feats + (size_t)b * CFEAT * NPTS;
    float4* xp4 = (float4*)(xall + (size_t)tid * 68);
    xp4[0] = make_float4(cb[p], cb[NPTS + p], cb[2 * NPTS + p], fb[p]);
#pragma unroll
    for (int r = 1; r < 16; ++r) {
        xp4[r] = make_float4(fb[(4 * r - 3) * NPTS + p], fb[(4 * r - 2) * NPTS + p],
                             fb[(4 * r - 1) * NPTS + p], fb[(4 * r) * NPTS + p]);
    }
    xp4[16] = make_float4(fb[61 * NPTS + p], fb[62 * NPTS + p], fb[63 * NPTS + p], 0.f);
}

// =====================================================================
// FPS v12: 1024 threads x 8 pts/thread (named scalars).
// STRATEGY FLIP after the R4-R9 campaign: the allocator's VGPR grant
// was never steerable (≈100 at 256thr, ≈48-56 at 512thr, regardless of
// pins/launders/scalars) -- so instead of raising the grant to meet
// demand, SHRINK DEMAND BELOW THE GRANT. At 1024 thr the per-thread
// state is only 8x4 = 32 floats (+~20 scratch ~= 52 total), plausibly
// under the grant for the first time -> private state genuinely
// register-resident, shuttle VALU vanishes. Total VALU issue/iter is
// conserved (1024x8 = 512x16) and 4 waves/SIMD hide the reduce/barrier
// latency better than 2. Combine widens to 16 slots (~+60cy).
// Tie-break bit-identical: bi = t + j*1024 ascending in j, strict >,
// u64 key (bv, NPTS-1-bi); no-contract fp32 distances match numpy.
// =====================================================================
#define FPS_REP(M) M(0) M(1) M(2) M(3) M(4) M(5) M(6) M(7)

__global__ __launch_bounds__(1024, 1) void fps_kernel(const float* __restrict__ coords,
                                                      int* __restrict__ cidx)
{
    extern __shared__ float smem[];
    float* sx = smem;
    float* sy = smem + NPTS;
    float* sz = smem + 2 * NPTS;
    unsigned long long* wpack = (unsigned long long*)(smem + 3 * NPTS);  // [2][16]

    const int b = blockIdx.x;
    const int t = threadIdx.x;
    const float* cb = coords + (size_t)b * 3 * NPTS;

#define FPS_DECL(J) float x##J, y##J, z##J, m##J;
    FPS_REP(FPS_DECL)

#define FPS_INIT(J) { \
        const int p = t + (J) * 1024; \
        x##J = cb[p]; y##J = cb[NPTS + p]; z##J = cb[2 * NPTS + p]; \
        float xv = x##J, yv = y##J, zv = z##J; \
        asm volatile("" : "+v"(xv), "+v"(yv), "+v"(zv)); \
        sx[p] = xv; sy[p] = yv; sz[p] = zv; \
        m##J = 1e10f; }
    FPS_REP(FPS_INIT)

    if (t == 0) cidx[b * NC] = 0;
    __syncthreads();

    int cur = 0;
    for (int it = 1; it < NC; ++it) {
        const float lx = sx[cur], ly = sy[cur], lz = sz[cur];  // broadcast
        float bv = -1.0f; int bi = 0;
#define FPS_STEP(J) { \
        float dx = __fsub_rn(x##J, lx); \
        float dy = __fsub_rn(y##J, ly); \
        float dz = __fsub_rn(z##J, lz); \
        float d  = __fadd_rn(__fadd_rn(__fmul_rn(dx, dx), __fmul_rn(dy, dy)), \
                             __fmul_rn(dz, dz)); \
        float nm = fminf(m##J, d); \
        m##J = nm; \
        if (nm > bv) { bv = nm; bi = t + (J) * 1024; } }   /* strict >: lowest idx */
        FPS_REP(FPS_STEP)

        // ---- intra-wave reduce: 6-step all-VALU DPP butterfly on u64 key ----
        unsigned hi = __float_as_uint(bv);                 // bv >= 0: uint order == float order
        unsigned lo = (unsigned)(NPTS - 1 - bi);           // larger lo == smaller index
        dppmax64<0x111>(hi, lo);   // row_shr:1
        dppmax64<0x112>(hi, lo);   // row_shr:2
        dppmax64<0x114>(hi, lo);   // row_shr:4
        dppmax64<0x118>(hi, lo);   // row_shr:8
        dppmax64<0x142>(hi, lo);   // row_bcast:15
        dppmax64<0x143>(hi, lo);   // row_bcast:31 -> lane63 has wave max
        unsigned long long pack = ((unsigned long long)hi << 32)
                                | (unsigned long long)lo;

        unsigned long long* wp = wpack + (it & 1) * 16;    // double buffer
        if ((t & 63) == 63) wp[t >> 6] = pack;             // winner is in lane 63
        __syncthreads();
        unsigned long long best = wp[0];
#pragma unroll
        for (int w = 1; w < 16; ++w) {
            unsigned long long v = wp[w];
            if (v > best) best = v;
        }
        cur = NPTS - 1 - (int)(best & 0xffffffffu);
        if (t == 0) cidx[b * NC + it] = cur;
    }
}

// =====================================================================
// Ball query v2 -> nidx + centers. EXPANDED d2 form (cn+pn)-2*cp, no
// fma. Single-pass distances: pass 1 records a 32-bit in-ball mask per
// thread; pass 2 walks set bits (ctz ascending = original ascending-j
// order) -- identical membership/selection, no distance recompute.
// =====================================================================
__global__ __launch_bounds__(256) void bq_kernel(const float* __restrict__ coords,
                                                 const int* __restrict__ cidx,
                                                 int* __restrict__ nidx,
                                                 float* __restrict__ centers)
{
    const int s = blockIdx.x, b = blockIdx.y, t = threadIdx.x;
    __shared__ int s_idx[KNN];
    __shared__ int s_pref[9];
    __shared__ float s_c[3];
    __shared__ float s_cn;
    const float* cb = coords + (size_t)b * 3 * NPTS;
    if (t == 0) {
        int ci = cidx[b * NC + s];
        float cx = cb[ci], cy = cb[NPTS + ci], cz = cb[2 * NPTS + ci];
        s_c[0] = cx; s_c[1] = cy; s_c[2] = cz;
        s_cn = __fadd_rn(__fadd_rn(__fmul_rn(cx, cx), __fmul_rn(cy, cy)),
                         __fmul_rn(cz, cz));
    }
    __syncthreads();
    const float cx = s_c[0], cy = s_c[1], cz = s_c[2], cn = s_cn;
    const int base = t * 32;
    int cnt = 0;
    unsigned msk = 0;
    for (int j = 0; j < 32; ++j) {
        int p = base + j;
        float x = cb[p], y = cb[NPTS + p], z = cb[2 * NPTS + p];
        float pn = __fadd_rn(__fadd_rn(__fmul_rn(x, x), __fmul_rn(y, y)), __fmul_rn(z, z));
        float cp = __fadd_rn(__fadd_rn(__fmul_rn(cx, x), __fmul_rn(cy, y)), __fmul_rn(cz, z));
        float d2 = __fsub_rn(__fadd_rn(cn, pn), __fmul_rn(2.0f, cp));
        if (d2 < R2) { ++cnt; msk |= 1u << j; }
    }
    const int lane = t & 63, wid = t >> 6;
    int incl = cnt;
    for (int o = 1; o < 64; o <<= 1) {
        int v = __shfl_up(incl, o);
        if (lane >= o) incl += v;
    }
    if (lane == 63) s_pref[wid] = incl;
    __syncthreads();
    int ex = incl - cnt;
    for (int w = 0; w < wid; ++w) ex += s_pref[w];
    if (t == 255) s_pref[8] = ex + cnt;
    if (ex < KNN && cnt > 0) {
        int slot = ex;
        unsigned mm = msk;
        while (mm && slot < KNN) {
            int j = __builtin_ctz(mm);
            mm &= mm - 1;
            s_idx[slot] = base + j;
            ++slot;
        }
    }
    __syncthreads();
    const int total = s_pref[8];
    if (t < KNN) {
        int v = (total == 0) ? 0 : ((t < total) ? s_idx[t] : s_idx[0]);
        nidx[(b * NC + s) * KNN + t] = v;
    }
    if (t < 3) centers[(b * NC + s) * 3 + t] = s_c[t];
}

// =====================================================================
// Layer 1: block = 64 cols x 4 out-chunks of 16. Gather staged in LDS
// xs[68][64] fp32; per-thread state is only acc[16] (no spill).
// =====================================================================
__global__ __launch_bounds__(256) void l1_kernel(const float* __restrict__ xall,
                                                 const int* __restrict__ nidx,
                                                 const float* __restrict__ centers,
                                                 const float* __restrict__ wt,
                                                 const float* __restrict__ b0,
                                                 float* __restrict__ Y,
                                                 float* __restrict__ statsPL)
{
    __shared__ float sw[67 * 64 + 64];
    __shared__ float xs[68 * 64];
    __shared__ float s_sum[8], s_sq[8];
    const int b = blockIdx.y, t = threadIdx.x;
    const int col = t & 63, q = t >> 6;
    const int n = blockIdx.x * 64 + col;
    for (int i = t; i < 67 * 64; i += 256) sw[i] = wt[i];
    if (t < 64) sw[67 * 64 + t] = b0[t];
    if (t < 8) { s_sum[t] = 0.f; s_sq[t] = 0.f; }
    const int s = n >> 5, k = n & 31;
    const int p = nidx[(b * NC + s) * KNN + k];
    const float4* xp4 = (const float4*)(xall + (size_t)(b * NPTS + p) * 68);
    const float* cc = centers + (size_t)(b * NC + s) * 3;
#pragma unroll
    for (int r = 0; r < 4; ++r) {
        float4 v = xp4[q * 4 + r];
        int ch = (q * 4 + r) * 4;
        if (ch == 0) { v.x -= cc[0]; v.y -= cc[1]; v.z -= cc[2]; }
        xs[(ch + 0) * 64 + col] = v.x;
        xs[(ch + 1) * 64 + col] = v.y;
        xs[(ch + 2) * 64 + col] = v.z;
        xs[(ch + 3) * 64 + col] = v.w;
    }
    if (q == 3) {
        float4 v = xp4[16];
        xs[64 * 64 + col] = v.x;
        xs[65 * 64 + col] = v.y;
        xs[66 * 64 + col] = v.z;
        xs[67 * 64 + col] = v.w;
    }
    __syncthreads();
    float acc[16];
#pragma unroll
    for (int o = 0; o < 16; ++o) acc[o] = sw[67 * 64 + q * 16 + o];
    for (int i = 0; i < 67; ++i) {
        float xv = xs[i * 64 + col];
        const float* wr = sw + i * 64 + q * 16;
#pragma unroll
        for (int o = 0; o < 16; ++o) acc[o] = fmaf(wr[o], xv, acc[o]);
    }
    float* yb = Y + (size_t)b * 64 * NSCOL + n;
#pragma unroll
    for (int o = 0; o < 16; ++o) yb[(size_t)(q * 16 + o) * NSCOL] = acc[o];
#pragma unroll
    for (int g = 0; g < 2; ++g) {
        float sv = 0.f, sq = 0.f;
#pragma unroll
        for (int j = 0; j < 8; ++j) { float vv = acc[g * 8 + j]; sv += vv; sq = fmaf(vv, vv, sq); }
#pragma unroll
        for (int o = 32; o > 0; o >>= 1) { sv += __shfl_xor(sv, o); sq += __shfl_xor(sq, o); }
        if ((t & 63) == 0) { atomicAdd(&s_sum[q * 2 + g], sv); atomicAdd(&s_sq[q * 2 + g], sq); }
    }
    __syncthreads();
    if (t < 16) {
        const int bin = blockIdx.x & (SBINS - 1);
        const int g = t >> 1, kk = t & 1;
        atomicAdd(&statsPL[bin * 128 + (b * 8 + g) * 2 + kk], kk ? s_sq[g] : s_sum[g]);
    }
}

// =====================================================================
// Layer 2: in-place, block = 64 cols x 4 out-chunks of 16.
// =====================================================================
__global__ __launch_bounds__(256) void l2_kernel(const float* __restrict__ wt1,
                                                 const float* __restrict__ b1,
                                                 const float* __restrict__ g0,
                                                 const float* __restrict__ be0,
                                                 const float* __restrict__ statsF_in,
                                                 float* __restrict__ statsPL,
                                                 float* __restrict__ Y)
{
    __shared__ float sw[64 * 64 + 64];
    __shared__ float xs[64 * 64];
    __shared__ float sA[64], sB[64];
    __shared__ float s_sum[8], s_sq[8];
    const int b = blockIdx.y, t = threadIdx.x;
    const int col = t & 63, q = t >> 6;
    const int n = blockIdx.x * 64 + col;
    for (int i = t; i < 64 * 64; i += 256) sw[i] = wt1[i];
    if (t < 64) {
        sw[64 * 64 + t] = b1[t];
        const int g = t >> 3;
        const float inv = 1.0f / (8.0f * NSCOL);
        float mu = statsF_in[(b * 8 + g) * 2 + 0] * inv;
        float var = statsF_in[(b * 8 + g) * 2 + 1] * inv - mu * mu;
        float A = (1.0f / sqrtf(var + GN_EPS)) * g0[t];
        sA[t] = A; sB[t] = be0[t] - mu * A;
    }
    if (t < 8) { s_sum[t] = 0.f; s_sq[t] = 0.f; }
    __syncthreads();
    float* yb = Y + (size_t)b * 64 * NSCOL + n;
#pragma unroll
    for (int r = 0; r < 16; ++r) {
        int i = q * 16 + r;
        float raw = yb[(size_t)i * NSCOL];
        float v = fmaf(raw, sA[i], sB[i]);
        xs[i * 64 + col] = v * __builtin_amdgcn_rcpf(1.0f + __expf(-v));
    }
    __syncthreads();
    float acc[16];
#pragma unroll
    for (int o = 0; o < 16; ++o) acc[o] = sw[64 * 64 + q * 16 + o];
    for (int i = 0; i < 64; ++i) {
        float xv = xs[i * 64 + col];
        const float* wr = sw + i * 64 + q * 16;
#pragma unroll
        for (int o = 0; o < 16; ++o) acc[o] = fmaf(wr[o], xv, acc[o]);
    }
#pragma unroll
    for (int o = 0; o < 16; ++o) yb[(size_t)(q * 16 + o) * NSCOL] = acc[o];
#pragma unroll
    for (int g = 0; g < 2; ++g) {
        float sv = 0.f, sq = 0.f;
#pragma unroll
        for (int j = 0; j < 8; ++j) { float vv = acc[g * 8 + j]; sv += vv; sq = fmaf(vv, vv, sq); }
#pragma unroll
        for (int o = 32; o > 0; o >>= 1) { sv += __shfl_xor(sv, o); sq += __shfl_xor(sq, o); }
        if ((t & 63) == 0) { atomicAdd(&s_sum[q * 2 + g], sv); atomicAdd(&s_sq[q * 2 + g], sq); }
    }
    __syncthreads();
    if (t < 16) {
        const int bin = blockIdx.x & (SBINS - 1);
        const int g = t >> 1, kk = t & 1;
        atomicAdd(&statsPL[bin * 128 + (b * 8 + g) * 2 + kk], kk ? s_sq[g] : s_sum[g]);
    }
}

// =====================================================================
// Layer 3: in-place, block = 64 cols x 4 out-chunks of 32 (128 out).
// Output bf16 pair-packed into the same 256B/col footprint.
// =====================================================================
__global__ __launch_bounds__(256) void l3_kernel(const float* __restrict__ wt2,
                                                 const float* __restrict__ b2,
                                                 const float* __restrict__ g1,
                                                 const float* __restrict__ be1,
                                                 const float* __restrict__ statsF_in,
                                                 float* __restrict__ statsPL,
                                                 float* __restrict__ Y)
{
    __shared__ float sw[64 * 128 + 128];
    __shared__ float xs[64 * 64];
    __shared__ float sA[64], sB[64];
    __shared__ float s_sum[8], s_sq[8];
    const int b = blockIdx.y, t = threadIdx.x;
    const int col = t & 63, q = t >> 6;
    const int n = blockIdx.x * 64 + col;
    for (int i = t; i < 64 * 128; i += 256) sw[i] = wt2[i];
    if (t < 128) sw[64 * 128 + t] = b2[t];
    if (t < 64) {
        const int g = t >> 3;
        const float inv = 1.0f / (8.0f * NSCOL);
        float mu = statsF_in[(b * 8 + g) * 2 + 0] * inv;
        float var = statsF_in[(b * 8 + g) * 2 + 1] * inv - mu * mu;
        float A = (1.0f / sqrtf(var + GN_EPS)) * g1[t];
        sA[t] = A; sB[t] = be1[t] - mu * A;
    }
    if (t < 8) { s_sum[t] = 0.f; s_sq[t] = 0.f; }
    __syncthreads();
    float* yb = Y + (size_t)b * 64 * NSCOL + n;
#pragma unroll
    for (int r = 0; r < 16; ++r) {
        int i = q * 16 + r;
        float raw = yb[(size_t)i * NSCOL];
        float v = fmaf(raw, sA[i], sB[i]);
        xs[i * 64 + col] = v * __builtin_amdgcn_rcpf(1.0f + __expf(-v));
    }
    __syncthreads();
    float acc[32];
#pragma unroll
    for (int o = 0; o < 32; ++o) acc[o] = sw[64 * 128 + q * 32 + o];
    for (int i = 0; i < 64; ++i) {
        float xv = xs[i * 64 + col];
        const float* wr = sw + i * 128 + q * 32;
#pragma unroll
        for (int o = 0; o < 32; ++o) acc[o] = fmaf(wr[o], xv, acc[o]);
    }
#pragma unroll
    for (int g = 0; g < 2; ++g) {
        float sv = 0.f, sq = 0.f;
#pragma unroll
        for (int j = 0; j < 16; ++j) { float vv = acc[g * 16 + j]; sv += vv; sq = fmaf(vv, vv, sq); }
#pragma unroll
        for (int o = 32; o > 0; o >>= 1) { sv += __shfl_xor(sv, o); sq += __shfl_xor(sq, o); }
        if ((t & 63) == 0) { atomicAdd(&s_sum[q * 2 + g], sv); atomicAdd(&s_sq[q * 2 + g], sq); }
    }
    unsigned* yu = (unsigned*)yb;
#pragma unroll
    for (int j = 0; j < 16; ++j) {
        unsigned u = f2bf(acc[2 * j]) | (f2bf(acc[2 * j + 1]) << 16);
        yu[(size_t)(q * 16 + j) * NSCOL] = u;
    }
    __syncthreads();
    if (t < 16) {
        const int bin = blockIdx.x & (SBINS - 1);
        const int g = t >> 1, kk = t & 1;
        atomicAdd(&statsPL[bin * 128 + (b * 8 + g) * 2 + kk], kk ? s_sq[g] : s_sum[g]);
    }
}

// =====================================================================
// Finalize: GN3 + SiLU + max over K. Thread per (b, channel-PAIR, s).
// =====================================================================
__global__ __launch_bounds__(256) void fin_kernel(const unsigned* __restrict__ Yu,
                                                  const float* __restrict__ g2,
                                                  const float* __restrict__ be2,
                                                  const float* __restrict__ stats,
                                                  float* __restrict__ out)
{
    const int tid = blockIdx.x * 256 + threadIdx.x;
    const int s = tid & (NC - 1);
    const int cp = (tid >> 11) & 63;
    const int b = tid >> 17;
    const int g = cp >> 3;
    const float inv = 1.0f / (16.0f * NSCOL);
    float mu = stats[(b * 8 + g) * 2 + 0] * inv;
    float var = stats[(b * 8 + g) * 2 + 1] * inv - mu * mu;
    float rs = 1.0f / sqrtf(var + GN_EPS);
    const int c0 = cp * 2, c1 = c0 + 1;
    float A0 = rs * g2[c0], B0 = be2[c0] - mu * A0;
    float A1 = rs * g2[c1], B1 = be2[c1] - mu * A1;
    const unsigned* yb = Yu + (size_t)(b * 64 + cp) * NSCOL + s * KNN;
    float m0 = -INFINITY, m1 = -INFINITY;
#pragma unroll
    for (int qq = 0; qq < 8; ++qq) {
        uint4 v = ((const uint4*)yb)[qq];
        unsigned uu[4] = {v.x, v.y, v.z, v.w};
#pragma unroll
        for (int r = 0; r < 4; ++r) {
            float f0 = __uint_as_float(uu[r] << 16);
            float f1 = __uint_as_float(uu[r] & 0xffff0000u);
            float v0 = fmaf(f0, A0, B0);
            v0 = v0 * __builtin_amdgcn_rcpf(1.0f + __expf(-v0));
            m0 = fmaxf(m0, v0);
            float v1 = fmaf(f1, A1, B1);
            v1 = v1 * __builtin_amdgcn_rcpf(1.0f + __expf(-v1));
            m1 = fmaxf(m1, v1);
        }
    }
    out[(size_t)(b * 128 + c0) * NC + s] = m0;
    out[(size_t)(b * 128 + c1) * NC + s] = m1;
}

// =====================================================================
extern "C" void kernel_launch(void* const* d_in, const int* in_sizes, int n_in,
                              void* d_out, int out_size, void* d_ws, size_t ws_size,
                              hipStream_t stream)
{
    if (ws_size < WS_NEEDED) return;

    const float* coords = (const float*)d_in[0];
    const float* feats  = (const float*)d_in[1];
    const float* w0  = (const float*)d_in[2];
    const float* b0  = (const float*)d_in[3];
    const float* g0  = (const float*)d_in[4];
    const float* be0 = (const float*)d_in[5];
    const float* w1  = (const float*)d_in[6];
    const float* b1  = (const float*)d_in[7];
    const float* g1  = (const float*)d_in[8];
    const float* be1 = (const float*)d_in[9];
    const float* w2  = (const float*)d_in[10];
    const float* b2  = (const float*)d_in[11];
    const float* g2  = (const float*)d_in[12];
    const float* be2 = (const float*)d_in[13];
    float* out = (float*)d_out;

    char* ws = (char*)d_ws;
    int*   cidx    = (int*)(ws + OFF_CIDX);
    int*   nidx    = (int*)(ws + OFF_NIDX);
    float* centers = (float*)(ws + OFF_CENT);
    float* statsP  = (float*)(ws + OFF_STATSP);   // [3][SBINS][128]
    float* statsF  = (float*)(ws + OFF_STATSF);   // [3][128]
    float* wt      = (float*)(ws + OFF_WT);
    float* xall    = (float*)(ws + OFF_XALL);
    float* Ybuf    = (float*)(ws + OFF_Y);

    prep_kernel<<<48, 256, 0, stream>>>(w0, w1, w2, statsP, statsF, wt);
    build_xall<<<(BATCH * NPTS) / 256, 256, 0, stream>>>(coords, feats, xall);
    // dynamic LDS: 3*NPTS floats (coords) + 32 u64 packs (2x16 dbuf)
    fps_kernel<<<BATCH, 1024, 3 * NPTS * 4 + 256, stream>>>(coords, cidx);
    bq_kernel<<<dim3(NC, BATCH), 256, 0, stream>>>(coords, cidx, nidx, centers);

    const dim3 lgrid(NSCOL / 64, BATCH);
    l1_kernel<<<lgrid, 256, 0, stream>>>(xall, nidx, centers, wt, b0, Ybuf, statsP);
    reduce_stats<<<1, 128, 0, stream>>>(statsP, statsF);
    l2_kernel<<<lgrid, 256, 0, stream>>>(wt + 4288, b1, g0, be0,
                                         statsF, statsP + SBINS * 128, Ybuf);
    reduce_stats<<<1, 128, 0, stream>>>(statsP + SBINS * 128, statsF + 128);
    l3_kernel<<<lgrid, 256, 0, stream>>>(wt + 8384, b2, g1, be1,
                                         statsF + 128, statsP + 2 * SBINS * 128, Ybuf);
    reduce_stats<<<1, 128, 0, stream>>>(statsP + 2 * SBINS * 128, statsF + 256);
    fin_kernel<<<(BATCH * 64 * NC) / 256, 256, 0, stream>>>(
        (const unsigned*)Ybuf, g2, be2, statsF + 256, out);
    (void)in_sizes; (void)n_in; (void)out_size;
}

// Round 12
// 2916.201 us; speedup vs baseline: 1.1188x; 1.1188x over previous
//
#include <hip/hip_runtime.h>
#include <math.h>

#define BATCH 8
#define NPTS 8192
#define CFEAT 64
#define NC 2048           // S centers
#define KNN 32
#define NSCOL (NC*KNN)    // 65536 columns per batch
#define R2 0.0625f        // radius^2
#define GN_EPS 1e-5f
#define SBINS 32          // stat partial bins (cuts atomic contention 32x)

// ---- workspace layout (bytes) ----
#define OFF_CIDX   0ull
#define OFF_NIDX   65536ull
#define OFF_CENT   2162688ull
#define OFF_STATSP 2359296ull            // 3 layers x 32 bins x 128 fl = 49152 B
#define OFF_STATSF 2408448ull            // 3 x 128 fl = 1536 B
#define OFF_WT     2410496ull            // 16576 fl = 66304 B
#define OFF_XALL   4194304ull            // 17,825,792 B
#define OFF_Y      23068672ull           // 134,217,728 B
#define WS_NEEDED  (OFF_Y + 8ull*64*NSCOL*4ull)   // 150 MiB

static __device__ __forceinline__ unsigned f2bf(float f) {
    unsigned u = __float_as_uint(f);
    return (u + 0x7fffu + ((u >> 16) & 1u)) >> 16;   // RNE, finite inputs
}

// ---- fused u64-key DPP max step: all-VALU, no readlane, no SALU ----
// partner = dpp(hi,lo); if (partner > mine) take partner.
// bound_ctrl=false + old=self: invalid-src lanes compare self>self -> keep.
template<int CTRL>
static __device__ __forceinline__ void dppmax64(unsigned& hi, unsigned& lo) {
    unsigned phi = (unsigned)__builtin_amdgcn_update_dpp((int)hi, (int)hi,
                                                         CTRL, 0xf, 0xf, false);
    unsigned plo = (unsigned)__builtin_amdgcn_update_dpp((int)lo, (int)lo,
                                                         CTRL, 0xf, 0xf, false);
    unsigned long long mine   = ((unsigned long long)hi  << 32) | lo;
    unsigned long long theirs = ((unsigned long long)phi << 32) | plo;
    if (theirs > mine) { hi = phi; lo = plo; }
}

// =====================================================================
// prep: zero stat partials/finals; transpose weights to [i][o] layout.
// =====================================================================
__global__ void prep_kernel(const float* __restrict__ w0, const float* __restrict__ w1,
                            const float* __restrict__ w2, float* __restrict__ statsP,
                            float* __restrict__ statsF, float* __restrict__ wt)
{
    const int t = blockIdx.x * 256 + threadIdx.x;
    if (t < 3 * SBINS * 128) statsP[t] = 0.f;
    if (t < 384) statsF[t] = 0.f;
    if (t < 64 * 67) { int o = t / 67, i = t - o * 67; wt[i * 64 + o] = w0[t]; }
    if (t < 64 * 64) { int o = t >> 6, i = t & 63;     wt[4288 + i * 64 + o] = w1[t]; }
    if (t < 128 * 64){ int o = t >> 6, i = t & 63;     wt[8384 + i * 128 + o] = w2[t]; }
}

// =====================================================================
__global__ void reduce_stats(const float* __restrict__ statsPL, float* __restrict__ statsFL)
{
    const int t = threadIdx.x;
    if (t < 128) {
        float s = 0.f;
#pragma unroll
        for (int bin = 0; bin < SBINS; ++bin) s += statsPL[bin * 128 + t];
        statsFL[t] = s;
    }
}

// =====================================================================
// build point-major input records: xall[b][p][0..2]=coords, [3..66]=feats,
// [67]=pad (272 B record, float4-aligned). float4-packed stores.
// =====================================================================
__global__ __launch_bounds__(256) void build_xall(const float* __restrict__ coords,
                                                  const float* __restrict__ feats,
                                                  float* __restrict__ xall)
{
    const int tid = blockIdx.x * 256 + threadIdx.x;   // b*NPTS + p
    const int b = tid >> 13, p = tid & (NPTS - 1);
    const float* cb = coords + (size_t)b * 3 * NPTS;
    const float* fb = feats + (size_t)b * CFEAT * NPTS;
    float4* xp4 = (float4*)(xall + (size_t)tid * 68);
    xp4[0] = make_float4(cb[p], cb[NPTS + p], cb[2 * NPTS + p], fb[p]);
#pragma unroll
    for (int r = 1; r < 16; ++r) {
        xp4[r] = make_float4(fb[(4 * r - 3) * NPTS + p], fb[(4 * r - 2) * NPTS + p],
                             fb[(4 * r - 1) * NPTS + p], fb[(4 * r) * NPTS + p]);
    }
    xp4[16] = make_float4(fb[61 * NPTS + p], fb[62 * NPTS + p], fb[63 * NPTS + p], 0.f);
}

// =====================================================================
// FPS v13: 512 threads x 16 pts/thread, coords in LDS as 16B RECORDS,
// re-read via ds_read_b128 each iteration.
// MODEL (from R4-R11 evidence): the allocator's VGPR grant is ~25K/
// block (100@256thr, 48@512thr, 28@1024thr) regardless of source form,
// so the 64-float coord working set NEVER fit -- the compiler re-reads
// coords from LDS every iteration as scalar ds_read_b32: 48 reads x
// 8 waves = 384 wave-insts/CU x ~5.8cy = 2227 cy/iter, matching the
// measured 2210 cy/iter. fps is LDS-ISSUE-bound, not VALU-bound.
// FIX: make the re-read vector, not resident: rec[p]={x,y,z,pad}
// (16B, float4) read as ONE ds_read_b128 per point (4x fewer LDS
// insts; conflict-free: consecutive lanes read consecutive 16B
// records, so each 8-lane phase covers all 32 banks). Private state
// shrinks to mind only (16 regs, finally under the 48 grant). No
// pins/launders needed -- LDS residence is now intentional.
// Floor: 8192x16B / 128 B/cy = 1024 cy + overhead ~= 1536 vs 2227.
// Tie-break and fp32 op order bit-identical to R8/R10: per point
// sub/sub/sub, mul/mul/mul, add/add, fmin, strict > with bi=t+j*512
// ascending in j; u64 key (bv, NPTS-1-bi); DPP butterfly reduce;
// 8-slot double-buffered combine.
// =====================================================================
#define FPS_REP(M) M(0) M(1) M(2) M(3) M(4) M(5) M(6) M(7) \
                   M(8) M(9) M(10) M(11) M(12) M(13) M(14) M(15)

__global__ __launch_bounds__(512, 1) void fps_kernel(const float* __restrict__ coords,
                                                     int* __restrict__ cidx)
{
    extern __shared__ float smem[];
    float4* rec = (float4*)smem;                                        // [NPTS]
    unsigned long long* wpack = (unsigned long long*)(smem + 4 * NPTS); // [2][8]

    const int b = blockIdx.x;
    const int t = threadIdx.x;
    const float* cb = coords + (size_t)b * 3 * NPTS;

#define FPS_DECL(J) float m##J;
    FPS_REP(FPS_DECL)

#define FPS_INIT(J) { \
        const int p = t + (J) * 512; \
        rec[p] = make_float4(cb[p], cb[NPTS + p], cb[2 * NPTS + p], 0.f); \
        m##J = 1e10f; }
    FPS_REP(FPS_INIT)

    if (t == 0) cidx[b * NC] = 0;
    __syncthreads();

    int cur = 0;
    for (int it = 1; it < NC; ++it) {
        const float4 c4 = rec[cur];                       // broadcast read
        const float lx = c4.x, ly = c4.y, lz = c4.z;
        float bv = -1.0f; int bi = 0;
#define FPS_STEP(J) { \
        const float4 r = rec[t + (J) * 512]; \
        float dx = __fsub_rn(r.x, lx); \
        float dy = __fsub_rn(r.y, ly); \
        float dz = __fsub_rn(r.z, lz); \
        float d  = __fadd_rn(__fadd_rn(__fmul_rn(dx, dx), __fmul_rn(dy, dy)), \
                             __fmul_rn(dz, dz)); \
        float nm = fminf(m##J, d); \
        m##J = nm; \
        if (nm > bv) { bv = nm; bi = t + (J) * 512; } }   /* strict >: lowest idx */
        FPS_REP(FPS_STEP)

        // ---- intra-wave reduce: 6-step all-VALU DPP butterfly on u64 key ----
        unsigned hi = __float_as_uint(bv);                 // bv >= 0: uint order == float order
        unsigned lo = (unsigned)(NPTS - 1 - bi);           // larger lo == smaller index
        dppmax64<0x111>(hi, lo);   // row_shr:1
        dppmax64<0x112>(hi, lo);   // row_shr:2
        dppmax64<0x114>(hi, lo);   // row_shr:4
        dppmax64<0x118>(hi, lo);   // row_shr:8
        dppmax64<0x142>(hi, lo);   // row_bcast:15
        dppmax64<0x143>(hi, lo);   // row_bcast:31 -> lane63 has wave max
        unsigned long long pack = ((unsigned long long)hi << 32)
                                | (unsigned long long)lo;

        unsigned long long* wp = wpack + (it & 1) * 8;     // double buffer
        if ((t & 63) == 63) wp[t >> 6] = pack;             // winner is in lane 63
        __syncthreads();
        unsigned long long best = wp[0];
#pragma unroll
        for (int w = 1; w < 8; ++w) {
            unsigned long long v = wp[w];
            if (v > best) best = v;
        }
        cur = NPTS - 1 - (int)(best & 0xffffffffu);
        if (t == 0) cidx[b * NC + it] = cur;
    }
}

// =====================================================================
// Ball query v2 -> nidx + centers. EXPANDED d2 form (cn+pn)-2*cp, no
// fma. Single-pass distances: pass 1 records a 32-bit in-ball mask per
// thread; pass 2 walks set bits (ctz ascending = original ascending-j
// order) -- identical membership/selection, no distance recompute.
// =====================================================================
__global__ __launch_bounds__(256) void bq_kernel(const float* __restrict__ coords,
                                                 const int* __restrict__ cidx,
                                                 int* __restrict__ nidx,
                                                 float* __restrict__ centers)
{
    const int s = blockIdx.x, b = blockIdx.y, t = threadIdx.x;
    __shared__ int s_idx[KNN];
    __shared__ int s_pref[9];
    __shared__ float s_c[3];
    __shared__ float s_cn;
    const float* cb = coords + (size_t)b * 3 * NPTS;
    if (t == 0) {
        int ci = cidx[b * NC + s];
        float cx = cb[ci], cy = cb[NPTS + ci], cz = cb[2 * NPTS + ci];
        s_c[0] = cx; s_c[1] = cy; s_c[2] = cz;
        s_cn = __fadd_rn(__fadd_rn(__fmul_rn(cx, cx), __fmul_rn(cy, cy)),
                         __fmul_rn(cz, cz));
    }
    __syncthreads();
    const float cx = s_c[0], cy = s_c[1], cz = s_c[2], cn = s_cn;
    const int base = t * 32;
    int cnt = 0;
    unsigned msk = 0;
    for (int j = 0; j < 32; ++j) {
        int p = base + j;
        float x = cb[p], y = cb[NPTS + p], z = cb[2 * NPTS + p];
        float pn = __fadd_rn(__fadd_rn(__fmul_rn(x, x), __fmul_rn(y, y)), __fmul_rn(z, z));
        float cp = __fadd_rn(__fadd_rn(__fmul_rn(cx, x), __fmul_rn(cy, y)), __fmul_rn(cz, z));
        float d2 = __fsub_rn(__fadd_rn(cn, pn), __fmul_rn(2.0f, cp));
        if (d2 < R2) { ++cnt; msk |= 1u << j; }
    }
    const int lane = t & 63, wid = t >> 6;
    int incl = cnt;
    for (int o = 1; o < 64; o <<= 1) {
        int v = __shfl_up(incl, o);
        if (lane >= o) incl += v;
    }
    if (lane == 63) s_pref[wid] = incl;
    __syncthreads();
    int ex = incl - cnt;
    for (int w = 0; w < wid; ++w) ex += s_pref[w];
    if (t == 255) s_pref[8] = ex + cnt;
    if (ex < KNN && cnt > 0) {
        int slot = ex;
        unsigned mm = msk;
        while (mm && slot < KNN) {
            int j = __builtin_ctz(mm);
            mm &= mm - 1;
            s_idx[slot] = base + j;
            ++slot;
        }
    }
    __syncthreads();
    const int total = s_pref[8];
    if (t < KNN) {
        int v = (total == 0) ? 0 : ((t < total) ? s_idx[t] : s_idx[0]);
        nidx[(b * NC + s) * KNN + t] = v;
    }
    if (t < 3) centers[(b * NC + s) * 3 + t] = s_c[t];
}

// =====================================================================
// Layer 1: block = 64 cols x 4 out-chunks of 16. Gather staged in LDS
// xs[68][64] fp32; per-thread state is only acc[16] (no spill).
// =====================================================================
__global__ __launch_bounds__(256) void l1_kernel(const float* __restrict__ xall,
                                                 const int* __restrict__ nidx,
                                                 const float* __restrict__ centers,
                                                 const float* __restrict__ wt,
                                                 const float* __restrict__ b0,
                                                 float* __restrict__ Y,
                                                 float* __restrict__ statsPL)
{
    __shared__ float sw[67 * 64 + 64];
    __shared__ float xs[68 * 64];
    __shared__ float s_sum[8], s_sq[8];
    const int b = blockIdx.y, t = threadIdx.x;
    const int col = t & 63, q = t >> 6;
    const int n = blockIdx.x * 64 + col;
    for (int i = t; i < 67 * 64; i += 256) sw[i] = wt[i];
    if (t < 64) sw[67 * 64 + t] = b0[t];
    if (t < 8) { s_sum[t] = 0.f; s_sq[t] = 0.f; }
    const int s = n >> 5, k = n & 31;
    const int p = nidx[(b * NC + s) * KNN + k];
    const float4* xp4 = (const float4*)(xall + (size_t)(b * NPTS + p) * 68);
    const float* cc = centers + (size_t)(b * NC + s) * 3;
#pragma unroll
    for (int r = 0; r < 4; ++r) {
        float4 v = xp4[q * 4 + r];
        int ch = (q * 4 + r) * 4;
        if (ch == 0) { v.x -= cc[0]; v.y -= cc[1]; v.z -= cc[2]; }
        xs[(ch + 0) * 64 + col] = v.x;
        xs[(ch + 1) * 64 + col] = v.y;
        xs[(ch + 2) * 64 + col] = v.z;
        xs[(ch + 3) * 64 + col] = v.w;
    }
    if (q == 3) {
        float4 v = xp4[16];
        xs[64 * 64 + col] = v.x;
        xs[65 * 64 + col] = v.y;
        xs[66 * 64 + col] = v.z;
        xs[67 * 64 + col] = v.w;
    }
    __syncthreads();
    float acc[16];
#pragma unroll
    for (int o = 0; o < 16; ++o) acc[o] = sw[67 * 64 + q * 16 + o];
    for (int i = 0; i < 67; ++i) {
        float xv = xs[i * 64 + col];
        const float* wr = sw + i * 64 + q * 16;
#pragma unroll
        for (int o = 0; o < 16; ++o) acc[o] = fmaf(wr[o], xv, acc[o]);
    }
    float* yb = Y + (size_t)b * 64 * NSCOL + n;
#pragma unroll
    for (int o = 0; o < 16; ++o) yb[(size_t)(q * 16 + o) * NSCOL] = acc[o];
#pragma unroll
    for (int g = 0; g < 2; ++g) {
        float sv = 0.f, sq = 0.f;
#pragma unroll
        for (int j = 0; j < 8; ++j) { float vv = acc[g * 8 + j]; sv += vv; sq = fmaf(vv, vv, sq); }
#pragma unroll
        for (int o = 32; o > 0; o >>= 1) { sv += __shfl_xor(sv, o); sq += __shfl_xor(sq, o); }
        if ((t & 63) == 0) { atomicAdd(&s_sum[q * 2 + g], sv); atomicAdd(&s_sq[q * 2 + g], sq); }
    }
    __syncthreads();
    if (t < 16) {
        const int bin = blockIdx.x & (SBINS - 1);
        const int g = t >> 1, kk = t & 1;
        atomicAdd(&statsPL[bin * 128 + (b * 8 + g) * 2 + kk], kk ? s_sq[g] : s_sum[g]);
    }
}

// =====================================================================
// Layer 2: in-place, block = 64 cols x 4 out-chunks of 16.
// =====================================================================
__global__ __launch_bounds__(256) void l2_kernel(const float* __restrict__ wt1,
                                                 const float* __restrict__ b1,
                                                 const float* __restrict__ g0,
                                                 const float* __restrict__ be0,
                                                 const float* __restrict__ statsF_in,
                                                 float* __restrict__ statsPL,
                                                 float* __restrict__ Y)
{
    __shared__ float sw[64 * 64 + 64];
    __shared__ float xs[64 * 64];
    __shared__ float sA[64], sB[64];
    __shared__ float s_sum[8], s_sq[8];
    const int b = blockIdx.y, t = threadIdx.x;
    const int col = t & 63, q = t >> 6;
    const int n = blockIdx.x * 64 + col;
    for (int i = t; i < 64 * 64; i += 256) sw[i] = wt1[i];
    if (t < 64) {
        sw[64 * 64 + t] = b1[t];
        const int g = t >> 3;
        const float inv = 1.0f / (8.0f * NSCOL);
        float mu = statsF_in[(b * 8 + g) * 2 + 0] * inv;
        float var = statsF_in[(b * 8 + g) * 2 + 1] * inv - mu * mu;
        float A = (1.0f / sqrtf(var + GN_EPS)) * g0[t];
        sA[t] = A; sB[t] = be0[t] - mu * A;
    }
    if (t < 8) { s_sum[t] = 0.f; s_sq[t] = 0.f; }
    __syncthreads();
    float* yb = Y + (size_t)b * 64 * NSCOL + n;
#pragma unroll
    for (int r = 0; r < 16; ++r) {
        int i = q * 16 + r;
        float raw = yb[(size_t)i * NSCOL];
        float v = fmaf(raw, sA[i], sB[i]);
        xs[i * 64 + col] = v * __builtin_amdgcn_rcpf(1.0f + __expf(-v));
    }
    __syncthreads();
    float acc[16];
#pragma unroll
    for (int o = 0; o < 16; ++o) acc[o] = sw[64 * 64 + q * 16 + o];
    for (int i = 0; i < 64; ++i) {
        float xv = xs[i * 64 + col];
        const float* wr = sw + i * 64 + q * 16;
#pragma unroll
        for (int o = 0; o < 16; ++o) acc[o] = fmaf(wr[o], xv, acc[o]);
    }
#pragma unroll
    for (int o = 0; o < 16; ++o) yb[(size_t)(q * 16 + o) * NSCOL] = acc[o];
#pragma unroll
    for (int g = 0; g < 2; ++g) {
        float sv = 0.f, sq = 0.f;
#pragma unroll
        for (int j = 0; j < 8; ++j) { float vv = acc[g * 8 + j]; sv += vv; sq = fmaf(vv, vv, sq); }
#pragma unroll
        for (int o = 32; o > 0; o >>= 1) { sv += __shfl_xor(sv, o); sq += __shfl_xor(sq, o); }
        if ((t & 63) == 0) { atomicAdd(&s_sum[q * 2 + g], sv); atomicAdd(&s_sq[q * 2 + g], sq); }
    }
    __syncthreads();
    if (t < 16) {
        const int bin = blockIdx.x & (SBINS - 1);
        const int g = t >> 1, kk = t & 1;
        atomicAdd(&statsPL[bin * 128 + (b * 8 + g) * 2 + kk], kk ? s_sq[g] : s_sum[g]);
    }
}

// =====================================================================
// Layer 3: in-place, block = 64 cols x 4 out-chunks of 32 (128 out).
// Output bf16 pair-packed into the same 256B/col footprint.
// =====================================================================
__global__ __launch_bounds__(256) void l3_kernel(const float* __restrict__ wt2,
                                                 const float* __restrict__ b2,
                                                 const float* __restrict__ g1,
                                                 const float* __restrict__ be1,
                                                 const float* __restrict__ statsF_in,
                                                 float* __restrict__ statsPL,
                                                 float* __restrict__ Y)
{
    __shared__ float sw[64 * 128 + 128];
    __shared__ float xs[64 * 64];
    __shared__ float sA[64], sB[64];
    __shared__ float s_sum[8], s_sq[8];
    const int b = blockIdx.y, t = threadIdx.x;
    const int col = t & 63, q = t >> 6;
    const int n = blockIdx.x * 64 + col;
    for (int i = t; i < 64 * 128; i += 256) sw[i] = wt2[i];
    if (t < 128) sw[64 * 128 + t] = b2[t];
    if (t < 64) {
        const int g = t >> 3;
        const float inv = 1.0f / (8.0f * NSCOL);
        float mu = statsF_in[(b * 8 + g) * 2 + 0] * inv;
        float var = statsF_in[(b * 8 + g) * 2 + 1] * inv - mu * mu;
        float A = (1.0f / sqrtf(var + GN_EPS)) * g1[t];
        sA[t] = A; sB[t] = be1[t] - mu * A;
    }
    if (t < 8) { s_sum[t] = 0.f; s_sq[t] = 0.f; }
    __syncthreads();
    float* yb = Y + (size_t)b * 64 * NSCOL + n;
#pragma unroll
    for (int r = 0; r < 16; ++r) {
        int i = q * 16 + r;
        float raw = yb[(size_t)i * NSCOL];
        float v = fmaf(raw, sA[i], sB[i]);
        xs[i * 64 + col] = v * __builtin_amdgcn_rcpf(1.0f + __expf(-v));
    }
    __syncthreads();
    float acc[32];
#pragma unroll
    for (int o = 0; o < 32; ++o) acc[o] = sw[64 * 128 + q * 32 + o];
    for (int i = 0; i < 64; ++i) {
        float xv = xs[i * 64 + col];
        const float* wr = sw + i * 128 + q * 32;
#pragma unroll
        for (int o = 0; o < 32; ++o) acc[o] = fmaf(wr[o], xv, acc[o]);
    }
#pragma unroll
    for (int g = 0; g < 2; ++g) {
        float sv = 0.f, sq = 0.f;
#pragma unroll
        for (int j = 0; j < 16; ++j) { float vv = acc[g * 16 + j]; sv += vv; sq = fmaf(vv, vv, sq); }
#pragma unroll
        for (int o = 32; o > 0; o >>= 1) { sv += __shfl_xor(sv, o); sq += __shfl_xor(sq, o); }
        if ((t & 63) == 0) { atomicAdd(&s_sum[q * 2 + g], sv); atomicAdd(&s_sq[q * 2 + g], sq); }
    }
    unsigned* yu = (unsigned*)yb;
#pragma unroll
    for (int j = 0; j < 16; ++j) {
        unsigned u = f2bf(acc[2 * j]) | (f2bf(acc[2 * j + 1]) << 16);
        yu[(size_t)(q * 16 + j) * NSCOL] = u;
    }
    __syncthreads();
    if (t < 16) {
        const int bin = blockIdx.x & (SBINS - 1);
        const int g = t >> 1, kk = t & 1;
        atomicAdd(&statsPL[bin * 128 + (b * 8 + g) * 2 + kk], kk ? s_sq[g] : s_sum[g]);
    }
}

// =====================================================================
// Finalize: GN3 + SiLU + max over K. Thread per (b, channel-PAIR, s).
// =====================================================================
__global__ __launch_bounds__(256) void fin_kernel(const unsigned* __restrict__ Yu,
                                                  const float* __restrict__ g2,
                                                  const float* __restrict__ be2,
                                                  const float* __restrict__ stats,
                                                  float* __restrict__ out)
{
    const int tid = blockIdx.x * 256 + threadIdx.x;
    const int s = tid & (NC - 1);
    const int cp = (tid >> 11) & 63;
    const int b = tid >> 17;
    const int g = cp >> 3;
    const float inv = 1.0f / (16.0f * NSCOL);
    float mu = stats[(b * 8 + g) * 2 + 0] * inv;
    float var = stats[(b * 8 + g) * 2 + 1] * inv - mu * mu;
    float rs = 1.0f / sqrtf(var + GN_EPS);
    const int c0 = cp * 2, c1 = c0 + 1;
    float A0 = rs * g2[c0], B0 = be2[c0] - mu * A0;
    float A1 = rs * g2[c1], B1 = be2[c1] - mu * A1;
    const unsigned* yb = Yu + (size_t)(b * 64 + cp) * NSCOL + s * KNN;
    float m0 = -INFINITY, m1 = -INFINITY;
#pragma unroll
    for (int qq = 0; qq < 8; ++qq) {
        uint4 v = ((const uint4*)yb)[qq];
        unsigned uu[4] = {v.x, v.y, v.z, v.w};
#pragma unroll
        for (int r = 0; r < 4; ++r) {
            float f0 = __uint_as_float(uu[r] << 16);
            float f1 = __uint_as_float(uu[r] & 0xffff0000u);
            float v0 = fmaf(f0, A0, B0);
            v0 = v0 * __builtin_amdgcn_rcpf(1.0f + __expf(-v0));
            m0 = fmaxf(m0, v0);
            float v1 = fmaf(f1, A1, B1);
            v1 = v1 * __builtin_amdgcn_rcpf(1.0f + __expf(-v1));
            m1 = fmaxf(m1, v1);
        }
    }
    out[(size_t)(b * 128 + c0) * NC + s] = m0;
    out[(size_t)(b * 128 + c1) * NC + s] = m1;
}

// =====================================================================
extern "C" void kernel_launch(void* const* d_in, const int* in_sizes, int n_in,
                              void* d_out, int out_size, void* d_ws, size_t ws_size,
                              hipStream_t stream)
{
    if (ws_size < WS_NEEDED) return;

    const float* coords = (const float*)d_in[0];
    const float* feats  = (const float*)d_in[1];
    const float* w0  = (const float*)d_in[2];
    const float* b0  = (const float*)d_in[3];
    const float* g0  = (const float*)d_in[4];
    const float* be0 = (const float*)d_in[5];
    const float* w1  = (const float*)d_in[6];
    const float* b1  = (const float*)d_in[7];
    const float* g1  = (const float*)d_in[8];
    const float* be1 = (const float*)d_in[9];
    const float* w2  = (const float*)d_in[10];
    const float* b2  = (const float*)d_in[11];
    const float* g2  = (const float*)d_in[12];
    const float* be2 = (const float*)d_in[13];
    float* out = (float*)d_out;

    char* ws = (char*)d_ws;
    int*   cidx    = (int*)(ws + OFF_CIDX);
    int*   nidx    = (int*)(ws + OFF_NIDX);
    float* centers = (float*)(ws + OFF_CENT);
    float* statsP  = (float*)(ws + OFF_STATSP);   // [3][SBINS][128]
    float* statsF  = (float*)(ws + OFF_STATSF);   // [3][128]
    float* wt      = (float*)(ws + OFF_WT);
    float* xall    = (float*)(ws + OFF_XALL);
    float* Ybuf    = (float*)(ws + OFF_Y);

    prep_kernel<<<48, 256, 0, stream>>>(w0, w1, w2, statsP, statsF, wt);
    build_xall<<<(BATCH * NPTS) / 256, 256, 0, stream>>>(coords, feats, xall);
    // dynamic LDS: NPTS float4 records (131072 B) + 16 u64 packs (128 B)
    fps_kernel<<<BATCH, 512, 4 * NPTS * 4 + 128, stream>>>(coords, cidx);
    bq_kernel<<<dim3(NC, BATCH), 256, 0, stream>>>(coords, cidx, nidx, centers);

    const dim3 lgrid(NSCOL / 64, BATCH);
    l1_kernel<<<lgrid, 256, 0, stream>>>(xall, nidx, centers, wt, b0, Ybuf, statsP);
    reduce_stats<<<1, 128, 0, stream>>>(statsP, statsF);
    l2_kernel<<<lgrid, 256, 0, stream>>>(wt + 4288, b1, g0, be0,
                                         statsF, statsP + SBINS * 128, Ybuf);
    reduce_stats<<<1, 128, 0, stream>>>(statsP + SBINS * 128, statsF + 128);
    l3_kernel<<<lgrid, 256, 0, stream>>>(wt + 8384, b2, g1, be1,
                                         statsF + 128, statsP + 2 * SBINS * 128, Ybuf);
    reduce_stats<<<1, 128, 0, stream>>>(statsP + 2 * SBINS * 128, statsF + 256);
    fin_kernel<<<(BATCH * 64 * NC) / 256, 256, 0, stream>>>(
        (const unsigned*)Ybuf, g2, be2, statsF + 256, out);
    (void)in_sizes; (void)n_in; (void)out_size;
}

// Round 13
// 2625.861 us; speedup vs baseline: 1.2426x; 1.1106x over previous
//
#include <hip/hip_runtime.h>
#include <math.h>

#define BATCH 8
#define NPTS 8192
#define CFEAT 64
#define NC 2048           // S centers
#define KNN 32
#define NSCOL (NC*KNN)    // 65536 columns per batch
#define R2 0.0625f        // radius^2
#define GN_EPS 1e-5f
#define SBINS 32          // stat partial bins (cuts atomic contention 32x)

// ---- workspace layout (bytes) ----
#define OFF_CIDX   0ull
#define OFF_NIDX   65536ull
#define OFF_CENT   2162688ull
#define OFF_STATSP 2359296ull            // 3 layers x 32 bins x 128 fl = 49152 B
#define OFF_STATSF 2408448ull            // 3 x 128 fl = 1536 B
#define OFF_WT     2410496ull            // 16576 fl = 66304 B
#define OFF_XALL   4194304ull            // 17,825,792 B
#define OFF_Y      23068672ull           // 134,217,728 B
#define WS_NEEDED  (OFF_Y + 8ull*64*NSCOL*4ull)   // 150 MiB

static __device__ __forceinline__ unsigned f2bf(float f) {
    unsigned u = __float_as_uint(f);
    return (u + 0x7fffu + ((u >> 16) & 1u)) >> 16;   // RNE, finite inputs
}

// ---- fused u64-key DPP max step: all-VALU, no readlane, no SALU ----
// partner = dpp(hi,lo); if (partner > mine) take partner.
// bound_ctrl=false + old=self: invalid-src lanes compare self>self -> keep.
template<int CTRL>
static __device__ __forceinline__ void dppmax64(unsigned& hi, unsigned& lo) {
    unsigned phi = (unsigned)__builtin_amdgcn_update_dpp((int)hi, (int)hi,
                                                         CTRL, 0xf, 0xf, false);
    unsigned plo = (unsigned)__builtin_amdgcn_update_dpp((int)lo, (int)lo,
                                                         CTRL, 0xf, 0xf, false);
    unsigned long long mine   = ((unsigned long long)hi  << 32) | lo;
    unsigned long long theirs = ((unsigned long long)phi << 32) | plo;
    if (theirs > mine) { hi = phi; lo = plo; }
}

// =====================================================================
// prep: zero stat partials/finals; transpose weights to [i][o] layout.
// =====================================================================
__global__ void prep_kernel(const float* __restrict__ w0, const float* __restrict__ w1,
                            const float* __restrict__ w2, float* __restrict__ statsP,
                            float* __restrict__ statsF, float* __restrict__ wt)
{
    const int t = blockIdx.x * 256 + threadIdx.x;
    if (t < 3 * SBINS * 128) statsP[t] = 0.f;
    if (t < 384) statsF[t] = 0.f;
    if (t < 64 * 67) { int o = t / 67, i = t - o * 67; wt[i * 64 + o] = w0[t]; }
    if (t < 64 * 64) { int o = t >> 6, i = t & 63;     wt[4288 + i * 64 + o] = w1[t]; }
    if (t < 128 * 64){ int o = t >> 6, i = t & 63;     wt[8384 + i * 128 + o] = w2[t]; }
}

// =====================================================================
__global__ void reduce_stats(const float* __restrict__ statsPL, float* __restrict__ statsFL)
{
    const int t = threadIdx.x;
    if (t < 128) {
        float s = 0.f;
#pragma unroll
        for (int bin = 0; bin < SBINS; ++bin) s += statsPL[bin * 128 + t];
        statsFL[t] = s;
    }
}

// =====================================================================
// build point-major input records: xall[b][p][0..2]=coords, [3..66]=feats,
// [67]=pad (272 B record, float4-aligned). float4-packed stores.
// =====================================================================
__global__ __launch_bounds__(256) void build_xall(const float* __restrict__ coords,
                                                  const float* __restrict__ feats,
                                                  float* __restrict__ xall)
{
    const int tid = blockIdx.x * 256 + threadIdx.x;   // b*NPTS + p
    const int b = tid >> 13, p = tid & (NPTS - 1);
    const float* cb = coords + (size_t)b * 3 * NPTS;
    const float* fb = feats + (size_t)b * CFEAT * NPTS;
    float4* xp4 = (float4*)(xall + (size_t)tid * 68);
    xp4[0] = make_float4(cb[p], cb[NPTS + p], cb[2 * NPTS + p], fb[p]);
#pragma unroll
    for (int r = 1; r < 16; ++r) {
        xp4[r] = make_float4(fb[(4 * r - 3) * NPTS + p], fb[(4 * r - 2) * NPTS + p],
                             fb[(4 * r - 1) * NPTS + p], fb[(4 * r) * NPTS + p]);
    }
    xp4[16] = make_float4(fb[61 * NPTS + p], fb[62 * NPTS + p], fb[63 * NPTS + p], 0.f);
}

// =====================================================================
// FPS (R8/R10-verbatim, best measured 1880us; campaign closed R4-R12):
// 512 threads, 16 pts/thread as named scalars; u64-key DPP butterfly
// reduce; 8-slot double-buffered cross-wave combine; one barrier/iter.
// The allocator grants ~25K VGPR/block regardless of source form; the
// R12 explicit-b128 variant regressed (2195us) -- this codegen is the
// floor. Tie-break (lowest global index via NPTS-1-bi key) and
// no-contract fp32 distance math bit-match numpy.
// =====================================================================
#define FPS_REP(M) M(0) M(1) M(2) M(3) M(4) M(5) M(6) M(7) \
                   M(8) M(9) M(10) M(11) M(12) M(13) M(14) M(15)

__global__ __launch_bounds__(512, 1) void fps_kernel(const float* __restrict__ coords,
                                                     int* __restrict__ cidx)
{
    extern __shared__ float smem[];
    float* sx = smem;
    float* sy = smem + NPTS;
    float* sz = smem + 2 * NPTS;
    unsigned long long* wpack = (unsigned long long*)(smem + 3 * NPTS);  // [2][8]

    const int b = blockIdx.x;
    const int t = threadIdx.x;
    const float* cb = coords + (size_t)b * 3 * NPTS;

#define FPS_DECL(J) float x##J, y##J, z##J, m##J;
    FPS_REP(FPS_DECL)

#define FPS_INIT(J) { \
        const int p = t + (J) * 512; \
        x##J = cb[p]; y##J = cb[NPTS + p]; z##J = cb[2 * NPTS + p]; \
        float xv = x##J, yv = y##J, zv = z##J; \
        asm volatile("" : "+v"(xv), "+v"(yv), "+v"(zv)); \
        sx[p] = xv; sy[p] = yv; sz[p] = zv; \
        m##J = 1e10f; }
    FPS_REP(FPS_INIT)

    if (t == 0) cidx[b * NC] = 0;
    __syncthreads();

    int cur = 0;
    for (int it = 1; it < NC; ++it) {
        const float lx = sx[cur], ly = sy[cur], lz = sz[cur];  // broadcast
        float bv = -1.0f; int bi = 0;
#define FPS_STEP(J) { \
        float dx = __fsub_rn(x##J, lx); \
        float dy = __fsub_rn(y##J, ly); \
        float dz = __fsub_rn(z##J, lz); \
        float d  = __fadd_rn(__fadd_rn(__fmul_rn(dx, dx), __fmul_rn(dy, dy)), \
                             __fmul_rn(dz, dz)); \
        float nm = fminf(m##J, d); \
        m##J = nm; \
        if (nm > bv) { bv = nm; bi = t + (J) * 512; } }   /* strict >: lowest idx */
        FPS_REP(FPS_STEP)

        // ---- intra-wave reduce: 6-step all-VALU DPP butterfly on u64 key ----
        unsigned hi = __float_as_uint(bv);                 // bv >= 0: uint order == float order
        unsigned lo = (unsigned)(NPTS - 1 - bi);           // larger lo == smaller index
        dppmax64<0x111>(hi, lo);   // row_shr:1
        dppmax64<0x112>(hi, lo);   // row_shr:2
        dppmax64<0x114>(hi, lo);   // row_shr:4
        dppmax64<0x118>(hi, lo);   // row_shr:8
        dppmax64<0x142>(hi, lo);   // row_bcast:15
        dppmax64<0x143>(hi, lo);   // row_bcast:31 -> lane63 has wave max
        unsigned long long pack = ((unsigned long long)hi << 32)
                                | (unsigned long long)lo;

        unsigned long long* wp = wpack + (it & 1) * 8;     // double buffer
        if ((t & 63) == 63) wp[t >> 6] = pack;             // winner is in lane 63
        __syncthreads();
        unsigned long long best = wp[0];
#pragma unroll
        for (int w = 1; w < 8; ++w) {
            unsigned long long v = wp[w];
            if (v > best) best = v;
        }
        cur = NPTS - 1 - (int)(best & 0xffffffffu);
        if (t == 0) cidx[b * NC + it] = cur;
    }
}

// =====================================================================
// Ball query v3 -> nidx + centers. COALESCED reads + ballot ordering.
// Old pattern: thread t owned p=t*32+j -> adjacent lanes 128B apart ->
// every 4B read pulled its own cache line (16-32x over-fetch), 96
// loads/thread x 16384 blocks. New: thread t reads p = j*256+t (lanes
// consecutive -> fully coalesced). Ordering: per j, __ballot(d2<R2)
// gives a 64-bit wave mask; storing masks at [j][wave] makes bit
// (mi,l) correspond to point p = mi*64+l, so ascending (mask,bit)
// order IS ascending global index order -- selection identical to the
// reference's stable argsort first-K. total = sum of popcounts.
// Distance math unchanged (expanded (cn+pn)-2cp, no fma).
// =====================================================================
__global__ __launch_bounds__(256) void bq_kernel(const float* __restrict__ coords,
                                                 const int* __restrict__ cidx,
                                                 int* __restrict__ nidx,
                                                 float* __restrict__ centers)
{
    const int s = blockIdx.x, b = blockIdx.y, t = threadIdx.x;
    __shared__ unsigned long long s_masks[32 * 4];   // [j][wave]
    __shared__ int s_idx[KNN];
    __shared__ int s_cnt[4];
    __shared__ float s_c[3];
    __shared__ float s_cn;
    const float* cb = coords + (size_t)b * 3 * NPTS;
    if (t == 0) {
        int ci = cidx[b * NC + s];
        float cx = cb[ci], cy = cb[NPTS + ci], cz = cb[2 * NPTS + ci];
        s_c[0] = cx; s_c[1] = cy; s_c[2] = cz;
        s_cn = __fadd_rn(__fadd_rn(__fmul_rn(cx, cx), __fmul_rn(cy, cy)),
                         __fmul_rn(cz, cz));
    }
    __syncthreads();
    const float cx = s_c[0], cy = s_c[1], cz = s_c[2], cn = s_cn;
    const int lane = t & 63, wid = t >> 6;
#pragma unroll 4
    for (int j = 0; j < 32; ++j) {
        const int p = j * 256 + t;                    // coalesced
        float x = cb[p], y = cb[NPTS + p], z = cb[2 * NPTS + p];
        float pn = __fadd_rn(__fadd_rn(__fmul_rn(x, x), __fmul_rn(y, y)), __fmul_rn(z, z));
        float cp = __fadd_rn(__fadd_rn(__fmul_rn(cx, x), __fmul_rn(cy, y)), __fmul_rn(cz, z));
        float d2 = __fsub_rn(__fadd_rn(cn, pn), __fmul_rn(2.0f, cp));
        unsigned long long mask = __ballot(d2 < R2);
        if (lane == 0) s_masks[j * 4 + wid] = mask;
    }
    __syncthreads();
    // total in-ball count: threads 0..127 popcount one mask each, wave-reduce
    int pc = (t < 128) ? __popcll(s_masks[t]) : 0;
#pragma unroll
    for (int o = 32; o > 0; o >>= 1) pc += __shfl_xor(pc, o);
    if (lane == 0) s_cnt[wid] = pc;
    // serial first-K extraction in ascending global-index order
    if (t == 0) {
        int slot = 0;
        for (int mi = 0; mi < 128 && slot < KNN; ++mi) {
            unsigned long long mm = s_masks[mi];
            const int base = mi * 64;                 // p = mi*64 + bit
            while (mm && slot < KNN) {
                int l = __ffsll((long long)mm) - 1;
                mm &= mm - 1;
                s_idx[slot++] = base + l;
            }
        }
    }
    __syncthreads();
    const int total = s_cnt[0] + s_cnt[1];            // masks 0..127 live in waves 0,1
    if (t < KNN) {
        int v = (total == 0) ? 0 : ((t < total) ? s_idx[t] : s_idx[0]);
        nidx[(b * NC + s) * KNN + t] = v;
    }
    if (t < 3) centers[(b * NC + s) * 3 + t] = s_c[t];
}

// =====================================================================
// Layer 1: block = 64 cols x 4 out-chunks of 16. Gather staged in LDS
// xs[68][64] fp32; per-thread state is only acc[16] (no spill).
// =====================================================================
__global__ __launch_bounds__(256) void l1_kernel(const float* __restrict__ xall,
                                                 const int* __restrict__ nidx,
                                                 const float* __restrict__ centers,
                                                 const float* __restrict__ wt,
                                                 const float* __restrict__ b0,
                                                 float* __restrict__ Y,
                                                 float* __restrict__ statsPL)
{
    __shared__ float sw[67 * 64 + 64];
    __shared__ float xs[68 * 64];
    __shared__ float s_sum[8], s_sq[8];
    const int b = blockIdx.y, t = threadIdx.x;
    const int col = t & 63, q = t >> 6;
    const int n = blockIdx.x * 64 + col;
    for (int i = t; i < 67 * 64; i += 256) sw[i] = wt[i];
    if (t < 64) sw[67 * 64 + t] = b0[t];
    if (t < 8) { s_sum[t] = 0.f; s_sq[t] = 0.f; }
    const int s = n >> 5, k = n & 31;
    const int p = nidx[(b * NC + s) * KNN + k];
    const float4* xp4 = (const float4*)(xall + (size_t)(b * NPTS + p) * 68);
    const float* cc = centers + (size_t)(b * NC + s) * 3;
#pragma unroll
    for (int r = 0; r < 4; ++r) {
        float4 v = xp4[q * 4 + r];
        int ch = (q * 4 + r) * 4;
        if (ch == 0) { v.x -= cc[0]; v.y -= cc[1]; v.z -= cc[2]; }
        xs[(ch + 0) * 64 + col] = v.x;
        xs[(ch + 1) * 64 + col] = v.y;
        xs[(ch + 2) * 64 + col] = v.z;
        xs[(ch + 3) * 64 + col] = v.w;
    }
    if (q == 3) {
        float4 v = xp4[16];
        xs[64 * 64 + col] = v.x;
        xs[65 * 64 + col] = v.y;
        xs[66 * 64 + col] = v.z;
        xs[67 * 64 + col] = v.w;
    }
    __syncthreads();
    float acc[16];
#pragma unroll
    for (int o = 0; o < 16; ++o) acc[o] = sw[67 * 64 + q * 16 + o];
    for (int i = 0; i < 67; ++i) {
        float xv = xs[i * 64 + col];
        const float* wr = sw + i * 64 + q * 16;
#pragma unroll
        for (int o = 0; o < 16; ++o) acc[o] = fmaf(wr[o], xv, acc[o]);
    }
    float* yb = Y + (size_t)b * 64 * NSCOL + n;
#pragma unroll
    for (int o = 0; o < 16; ++o) yb[(size_t)(q * 16 + o) * NSCOL] = acc[o];
#pragma unroll
    for (int g = 0; g < 2; ++g) {
        float sv = 0.f, sq = 0.f;
#pragma unroll
        for (int j = 0; j < 8; ++j) { float vv = acc[g * 8 + j]; sv += vv; sq = fmaf(vv, vv, sq); }
#pragma unroll
        for (int o = 32; o > 0; o >>= 1) { sv += __shfl_xor(sv, o); sq += __shfl_xor(sq, o); }
        if ((t & 63) == 0) { atomicAdd(&s_sum[q * 2 + g], sv); atomicAdd(&s_sq[q * 2 + g], sq); }
    }
    __syncthreads();
    if (t < 16) {
        const int bin = blockIdx.x & (SBINS - 1);
        const int g = t >> 1, kk = t & 1;
        atomicAdd(&statsPL[bin * 128 + (b * 8 + g) * 2 + kk], kk ? s_sq[g] : s_sum[g]);
    }
}

// =====================================================================
// Layer 2: in-place, block = 64 cols x 4 out-chunks of 16.
// =====================================================================
__global__ __launch_bounds__(256) void l2_kernel(const float* __restrict__ wt1,
                                                 const float* __restrict__ b1,
                                                 const float* __restrict__ g0,
                                                 const float* __restrict__ be0,
                                                 const float* __restrict__ statsF_in,
                                                 float* __restrict__ statsPL,
                                                 float* __restrict__ Y)
{
    __shared__ float sw[64 * 64 + 64];
    __shared__ float xs[64 * 64];
    __shared__ float sA[64], sB[64];
    __shared__ float s_sum[8], s_sq[8];
    const int b = blockIdx.y, t = threadIdx.x;
    const int col = t & 63, q = t >> 6;
    const int n = blockIdx.x * 64 + col;
    for (int i = t; i < 64 * 64; i += 256) sw[i] = wt1[i];
    if (t < 64) {
        sw[64 * 64 + t] = b1[t];
        const int g = t >> 3;
        const float inv = 1.0f / (8.0f * NSCOL);
        float mu = statsF_in[(b * 8 + g) * 2 + 0] * inv;
        float var = statsF_in[(b * 8 + g) * 2 + 1] * inv - mu * mu;
        float A = (1.0f / sqrtf(var + GN_EPS)) * g0[t];
        sA[t] = A; sB[t] = be0[t] - mu * A;
    }
    if (t < 8) { s_sum[t] = 0.f; s_sq[t] = 0.f; }
    __syncthreads();
    float* yb = Y + (size_t)b * 64 * NSCOL + n;
#pragma unroll
    for (int r = 0; r < 16; ++r) {
        int i = q * 16 + r;
        float raw = yb[(size_t)i * NSCOL];
        float v = fmaf(raw, sA[i], sB[i]);
        xs[i * 64 + col] = v * __builtin_amdgcn_rcpf(1.0f + __expf(-v));
    }
    __syncthreads();
    float acc[16];
#pragma unroll
    for (int o = 0; o < 16; ++o) acc[o] = sw[64 * 64 + q * 16 + o];
    for (int i = 0; i < 64; ++i) {
        float xv = xs[i * 64 + col];
        const float* wr = sw + i * 64 + q * 16;
#pragma unroll
        for (int o = 0; o < 16; ++o) acc[o] = fmaf(wr[o], xv, acc[o]);
    }
#pragma unroll
    for (int o = 0; o < 16; ++o) yb[(size_t)(q * 16 + o) * NSCOL] = acc[o];
#pragma unroll
    for (int g = 0; g < 2; ++g) {
        float sv = 0.f, sq = 0.f;
#pragma unroll
        for (int j = 0; j < 8; ++j) { float vv = acc[g * 8 + j]; sv += vv; sq = fmaf(vv, vv, sq); }
#pragma unroll
        for (int o = 32; o > 0; o >>= 1) { sv += __shfl_xor(sv, o); sq += __shfl_xor(sq, o); }
        if ((t & 63) == 0) { atomicAdd(&s_sum[q * 2 + g], sv); atomicAdd(&s_sq[q * 2 + g], sq); }
    }
    __syncthreads();
    if (t < 16) {
        const int bin = blockIdx.x & (SBINS - 1);
        const int g = t >> 1, kk = t & 1;
        atomicAdd(&statsPL[bin * 128 + (b * 8 + g) * 2 + kk], kk ? s_sq[g] : s_sum[g]);
    }
}

// =====================================================================
// Layer 3: in-place, block = 64 cols x 4 out-chunks of 32 (128 out).
// Output bf16 pair-packed into the same 256B/col footprint.
// =====================================================================
__global__ __launch_bounds__(256) void l3_kernel(const float* __restrict__ wt2,
                                                 const float* __restrict__ b2,
                                                 const float* __restrict__ g1,
                                                 const float* __restrict__ be1,
                                                 const float* __restrict__ statsF_in,
                                                 float* __restrict__ statsPL,
                                                 float* __restrict__ Y)
{
    __shared__ float sw[64 * 128 + 128];
    __shared__ float xs[64 * 64];
    __shared__ float sA[64], sB[64];
    __shared__ float s_sum[8], s_sq[8];
    const int b = blockIdx.y, t = threadIdx.x;
    const int col = t & 63, q = t >> 6;
    const int n = blockIdx.x * 64 + col;
    for (int i = t; i < 64 * 128; i += 256) sw[i] = wt2[i];
    if (t < 128) sw[64 * 128 + t] = b2[t];
    if (t < 64) {
        const int g = t >> 3;
        const float inv = 1.0f / (8.0f * NSCOL);
        float mu = statsF_in[(b * 8 + g) * 2 + 0] * inv;
        float var = statsF_in[(b * 8 + g) * 2 + 1] * inv - mu * mu;
        float A = (1.0f / sqrtf(var + GN_EPS)) * g1[t];
        sA[t] = A; sB[t] = be1[t] - mu * A;
    }
    if (t < 8) { s_sum[t] = 0.f; s_sq[t] = 0.f; }
    __syncthreads();
    float* yb = Y + (size_t)b * 64 * NSCOL + n;
#pragma unroll
    for (int r = 0; r < 16; ++r) {
        int i = q * 16 + r;
        float raw = yb[(size_t)i * NSCOL];
        float v = fmaf(raw, sA[i], sB[i]);
        xs[i * 64 + col] = v * __builtin_amdgcn_rcpf(1.0f + __expf(-v));
    }
    __syncthreads();
    float acc[32];
#pragma unroll
    for (int o = 0; o < 32; ++o) acc[o] = sw[64 * 128 + q * 32 + o];
    for (int i = 0; i < 64; ++i) {
        float xv = xs[i * 64 + col];
        const float* wr = sw + i * 128 + q * 32;
#pragma unroll
        for (int o = 0; o < 32; ++o) acc[o] = fmaf(wr[o], xv, acc[o]);
    }
#pragma unroll
    for (int g = 0; g < 2; ++g) {
        float sv = 0.f, sq = 0.f;
#pragma unroll
        for (int j = 0; j < 16; ++j) { float vv = acc[g * 16 + j]; sv += vv; sq = fmaf(vv, vv, sq); }
#pragma unroll
        for (int o = 32; o > 0; o >>= 1) { sv += __shfl_xor(sv, o); sq += __shfl_xor(sq, o); }
        if ((t & 63) == 0) { atomicAdd(&s_sum[q * 2 + g], sv); atomicAdd(&s_sq[q * 2 + g], sq); }
    }
    unsigned* yu = (unsigned*)yb;
#pragma unroll
    for (int j = 0; j < 16; ++j) {
        unsigned u = f2bf(acc[2 * j]) | (f2bf(acc[2 * j + 1]) << 16);
        yu[(size_t)(q * 16 + j) * NSCOL] = u;
    }
    __syncthreads();
    if (t < 16) {
        const int bin = blockIdx.x & (SBINS - 1);
        const int g = t >> 1, kk = t & 1;
        atomicAdd(&statsPL[bin * 128 + (b * 8 + g) * 2 + kk], kk ? s_sq[g] : s_sum[g]);
    }
}

// =====================================================================
// Finalize: GN3 + SiLU + max over K. Thread per (b, channel-PAIR, s).
// =====================================================================
__global__ __launch_bounds__(256) void fin_kernel(const unsigned* __restrict__ Yu,
                                                  const float* __restrict__ g2,
                                                  const float* __restrict__ be2,
                                                  const float* __restrict__ stats,
                                                  float* __restrict__ out)
{
    const int tid = blockIdx.x * 256 + threadIdx.x;
    const int s = tid & (NC - 1);
    const int cp = (tid >> 11) & 63;
    const int b = tid >> 17;
    const int g = cp >> 3;
    const float inv = 1.0f / (16.0f * NSCOL);
    float mu = stats[(b * 8 + g) * 2 + 0] * inv;
    float var = stats[(b * 8 + g) * 2 + 1] * inv - mu * mu;
    float rs = 1.0f / sqrtf(var + GN_EPS);
    const int c0 = cp * 2, c1 = c0 + 1;
    float A0 = rs * g2[c0], B0 = be2[c0] - mu * A0;
    float A1 = rs * g2[c1], B1 = be2[c1] - mu * A1;
    const unsigned* yb = Yu + (size_t)(b * 64 + cp) * NSCOL + s * KNN;
    float m0 = -INFINITY, m1 = -INFINITY;
#pragma unroll
    for (int qq = 0; qq < 8; ++qq) {
        uint4 v = ((const uint4*)yb)[qq];
        unsigned uu[4] = {v.x, v.y, v.z, v.w};
#pragma unroll
        for (int r = 0; r < 4; ++r) {
            float f0 = __uint_as_float(uu[r] << 16);
            float f1 = __uint_as_float(uu[r] & 0xffff0000u);
            float v0 = fmaf(f0, A0, B0);
            v0 = v0 * __builtin_amdgcn_rcpf(1.0f + __expf(-v0));
            m0 = fmaxf(m0, v0);
            float v1 = fmaf(f1, A1, B1);
            v1 = v1 * __builtin_amdgcn_rcpf(1.0f + __expf(-v1));
            m1 = fmaxf(m1, v1);
        }
    }
    out[(size_t)(b * 128 + c0) * NC + s] = m0;
    out[(size_t)(b * 128 + c1) * NC + s] = m1;
}

// =====================================================================
extern "C" void kernel_launch(void* const* d_in, const int* in_sizes, int n_in,
                              void* d_out, int out_size, void* d_ws, size_t ws_size,
                              hipStream_t stream)
{
    if (ws_size < WS_NEEDED) return;

    const float* coords = (const float*)d_in[0];
    const float* feats  = (const float*)d_in[1];
    const float* w0  = (const float*)d_in[2];
    const float* b0  = (const float*)d_in[3];
    const float* g0  = (const float*)d_in[4];
    const float* be0 = (const float*)d_in[5];
    const float* w1  = (const float*)d_in[6];
    const float* b1  = (const float*)d_in[7];
    const float* g1  = (const float*)d_in[8];
    const float* be1 = (const float*)d_in[9];
    const float* w2  = (const float*)d_in[10];
    const float* b2  = (const float*)d_in[11];
    const float* g2  = (const float*)d_in[12];
    const float* be2 = (const float*)d_in[13];
    float* out = (float*)d_out;

    char* ws = (char*)d_ws;
    int*   cidx    = (int*)(ws + OFF_CIDX);
    int*   nidx    = (int*)(ws + OFF_NIDX);
    float* centers = (float*)(ws + OFF_CENT);
    float* statsP  = (float*)(ws + OFF_STATSP);   // [3][SBINS][128]
    float* statsF  = (float*)(ws + OFF_STATSF);   // [3][128]
    float* wt      = (float*)(ws + OFF_WT);
    float* xall    = (float*)(ws + OFF_XALL);
    float* Ybuf    = (float*)(ws + OFF_Y);

    prep_kernel<<<48, 256, 0, stream>>>(w0, w1, w2, statsP, statsF, wt);
    build_xall<<<(BATCH * NPTS) / 256, 256, 0, stream>>>(coords, feats, xall);
    // dynamic LDS: 3*NPTS floats (coords) + 16 u64 packs (2x8 dbuf)
    fps_kernel<<<BATCH, 512, 3 * NPTS * 4 + 128, stream>>>(coords, cidx);
    bq_kernel<<<dim3(NC, BATCH), 256, 0, stream>>>(coords, cidx, nidx, centers);

    const dim3 lgrid(NSCOL / 64, BATCH);
    l1_kernel<<<lgrid, 256, 0, stream>>>(xall, nidx, centers, wt, b0, Ybuf, statsP);
    reduce_stats<<<1, 128, 0, stream>>>(statsP, statsF);
    l2_kernel<<<lgrid, 256, 0, stream>>>(wt + 4288, b1, g0, be0,
                                         statsF, statsP + SBINS * 128, Ybuf);
    reduce_stats<<<1, 128, 0, stream>>>(statsP + SBINS * 128, statsF + 128);
    l3_kernel<<<lgrid, 256, 0, stream>>>(wt + 8384, b2, g1, be1,
                                         statsF + 128, statsP + 2 * SBINS * 128, Ybuf);
    reduce_stats<<<1, 128, 0, stream>>>(statsP + 2 * SBINS * 128, statsF + 256);
    fin_kernel<<<(BATCH * 64 * NC) / 256, 256, 0, stream>>>(
        (const unsigned*)Ybuf, g2, be2, statsF + 256, out);
    (void)in_sizes; (void)n_in; (void)out_size;
}

// Round 14
// 2602.776 us; speedup vs baseline: 1.2536x; 1.0089x over previous
//
#include <hip/hip_runtime.h>
#include <math.h>

#define BATCH 8
#define NPTS 8192
#define CFEAT 64
#define NC 2048           // S centers
#define KNN 32
#define NSCOL (NC*KNN)    // 65536 columns per batch
#define R2 0.0625f        // radius^2
#define GN_EPS 1e-5f
#define SBINS 32          // stat partial bins (cuts atomic contention 32x)

// ---- workspace layout (bytes) ----
#define OFF_CIDX   0ull
#define OFF_NIDX   65536ull
#define OFF_CENT   2162688ull
#define OFF_STATSP 2359296ull            // 3 layers x 32 bins x 128 fl = 49152 B
#define OFF_WT     2410496ull            // 16576 fl = 66304 B
#define OFF_XALL   4194304ull            // 17,825,792 B
#define OFF_Y      23068672ull           // 134,217,728 B
#define WS_NEEDED  (OFF_Y + 8ull*64*NSCOL*4ull)   // 150 MiB

static __device__ __forceinline__ unsigned f2bf(float f) {
    unsigned u = __float_as_uint(f);
    return (u + 0x7fffu + ((u >> 16) & 1u)) >> 16;   // RNE, finite inputs
}

// ---- fused u64-key DPP max step: all-VALU, no readlane, no SALU ----
// partner = dpp(hi,lo); if (partner > mine) take partner.
// bound_ctrl=false + old=self: invalid-src lanes compare self>self -> keep.
template<int CTRL>
static __device__ __forceinline__ void dppmax64(unsigned& hi, unsigned& lo) {
    unsigned phi = (unsigned)__builtin_amdgcn_update_dpp((int)hi, (int)hi,
                                                         CTRL, 0xf, 0xf, false);
    unsigned plo = (unsigned)__builtin_amdgcn_update_dpp((int)lo, (int)lo,
                                                         CTRL, 0xf, 0xf, false);
    unsigned long long mine   = ((unsigned long long)hi  << 32) | lo;
    unsigned long long theirs = ((unsigned long long)phi << 32) | plo;
    if (theirs > mine) { hi = phi; lo = plo; }
}

// =====================================================================
// build_xall + prep (merged, one launch): zero stat partials; transpose
// weights to [i][o]; build point-major records xall[b][p][0..2]=coords,
// [3..66]=feats, [67]=pad (272B record, float4-aligned, packed stores).
// All consumers (fps/bq don't touch these; l1+ do) are later kernels,
// so kernel-boundary visibility is unchanged vs the separate prep.
// =====================================================================
__global__ __launch_bounds__(256) void build_xall(const float* __restrict__ coords,
                                                  const float* __restrict__ feats,
                                                  const float* __restrict__ w0,
                                                  const float* __restrict__ w1,
                                                  const float* __restrict__ w2,
                                                  float* __restrict__ statsP,
                                                  float* __restrict__ wt,
                                                  float* __restrict__ xall)
{
    const int tid = blockIdx.x * 256 + threadIdx.x;   // b*NPTS + p
    // ---- prep duties (low tids) ----
    if (tid < 3 * SBINS * 128) statsP[tid] = 0.f;
    if (tid < 64 * 67) { int o = tid / 67, i = tid - o * 67; wt[i * 64 + o] = w0[tid]; }
    if (tid < 64 * 64) { int o = tid >> 6, i = tid & 63;     wt[4288 + i * 64 + o] = w1[tid]; }
    if (tid < 128 * 64){ int o = tid >> 6, i = tid & 63;     wt[8384 + i * 128 + o] = w2[tid]; }
    // ---- record build ----
    const int b = tid >> 13, p = tid & (NPTS - 1);
    const float* cb = coords + (size_t)b * 3 * NPTS;
    const float* fb = feats + (size_t)b * CFEAT * NPTS;
    float4* xp4 = (float4*)(xall + (size_t)tid * 68);
    xp4[0] = make_float4(cb[p], cb[NPTS + p], cb[2 * NPTS + p], fb[p]);
#pragma unroll
    for (int r = 1; r < 16; ++r) {
        xp4[r] = make_float4(fb[(4 * r - 3) * NPTS + p], fb[(4 * r - 2) * NPTS + p],
                             fb[(4 * r - 1) * NPTS + p], fb[(4 * r) * NPTS + p]);
    }
    xp4[16] = make_float4(fb[61 * NPTS + p], fb[62 * NPTS + p], fb[63 * NPTS + p], 0.f);
}

// =====================================================================
// FPS (R8/R10-verbatim, best measured 1880us; campaign closed R4-R12):
// 512 threads, 16 pts/thread as named scalars; u64-key DPP butterfly
// reduce; 8-slot double-buffered cross-wave combine; one barrier/iter.
// The allocator grants ~25K VGPR/block regardless of source form; the
// R12 explicit-b128 variant regressed (2195us) -- this codegen is the
// floor. Tie-break (lowest global index via NPTS-1-bi key) and
// no-contract fp32 distance math bit-match numpy.
// =====================================================================
#define FPS_REP(M) M(0) M(1) M(2) M(3) M(4) M(5) M(6) M(7) \
                   M(8) M(9) M(10) M(11) M(12) M(13) M(14) M(15)

__global__ __launch_bounds__(512, 1) void fps_kernel(const float* __restrict__ coords,
                                                     int* __restrict__ cidx)
{
    extern __shared__ float smem[];
    float* sx = smem;
    float* sy = smem + NPTS;
    float* sz = smem + 2 * NPTS;
    unsigned long long* wpack = (unsigned long long*)(smem + 3 * NPTS);  // [2][8]

    const int b = blockIdx.x;
    const int t = threadIdx.x;
    const float* cb = coords + (size_t)b * 3 * NPTS;

#define FPS_DECL(J) float x##J, y##J, z##J, m##J;
    FPS_REP(FPS_DECL)

#define FPS_INIT(J) { \
        const int p = t + (J) * 512; \
        x##J = cb[p]; y##J = cb[NPTS + p]; z##J = cb[2 * NPTS + p]; \
        float xv = x##J, yv = y##J, zv = z##J; \
        asm volatile("" : "+v"(xv), "+v"(yv), "+v"(zv)); \
        sx[p] = xv; sy[p] = yv; sz[p] = zv; \
        m##J = 1e10f; }
    FPS_REP(FPS_INIT)

    if (t == 0) cidx[b * NC] = 0;
    __syncthreads();

    int cur = 0;
    for (int it = 1; it < NC; ++it) {
        const float lx = sx[cur], ly = sy[cur], lz = sz[cur];  // broadcast
        float bv = -1.0f; int bi = 0;
#define FPS_STEP(J) { \
        float dx = __fsub_rn(x##J, lx); \
        float dy = __fsub_rn(y##J, ly); \
        float dz = __fsub_rn(z##J, lz); \
        float d  = __fadd_rn(__fadd_rn(__fmul_rn(dx, dx), __fmul_rn(dy, dy)), \
                             __fmul_rn(dz, dz)); \
        float nm = fminf(m##J, d); \
        m##J = nm; \
        if (nm > bv) { bv = nm; bi = t + (J) * 512; } }   /* strict >: lowest idx */
        FPS_REP(FPS_STEP)

        // ---- intra-wave reduce: 6-step all-VALU DPP butterfly on u64 key ----
        unsigned hi = __float_as_uint(bv);                 // bv >= 0: uint order == float order
        unsigned lo = (unsigned)(NPTS - 1 - bi);           // larger lo == smaller index
        dppmax64<0x111>(hi, lo);   // row_shr:1
        dppmax64<0x112>(hi, lo);   // row_shr:2
        dppmax64<0x114>(hi, lo);   // row_shr:4
        dppmax64<0x118>(hi, lo);   // row_shr:8
        dppmax64<0x142>(hi, lo);   // row_bcast:15
        dppmax64<0x143>(hi, lo);   // row_bcast:31 -> lane63 has wave max
        unsigned long long pack = ((unsigned long long)hi << 32)
                                | (unsigned long long)lo;

        unsigned long long* wp = wpack + (it & 1) * 8;     // double buffer
        if ((t & 63) == 63) wp[t >> 6] = pack;             // winner is in lane 63
        __syncthreads();
        unsigned long long best = wp[0];
#pragma unroll
        for (int w = 1; w < 8; ++w) {
            unsigned long long v = wp[w];
            if (v > best) best = v;
        }
        cur = NPTS - 1 - (int)(best & 0xffffffffu);
        if (t == 0) cidx[b * NC + it] = cur;
    }
}

// =====================================================================
// Ball query (R10-verbatim v2) -> nidx + centers. EXPANDED d2 form
// (cn+pn)-2*cp, no fma. Single-pass distances: pass 1 records a 32-bit
// in-ball mask per thread; pass 2 walks set bits (ctz ascending =
// original ascending-j order) -- identical membership/selection.
// =====================================================================
__global__ __launch_bounds__(256) void bq_kernel(const float* __restrict__ coords,
                                                 const int* __restrict__ cidx,
                                                 int* __restrict__ nidx,
                                                 float* __restrict__ centers)
{
    const int s = blockIdx.x, b = blockIdx.y, t = threadIdx.x;
    __shared__ int s_idx[KNN];
    __shared__ int s_pref[9];
    __shared__ float s_c[3];
    __shared__ float s_cn;
    const float* cb = coords + (size_t)b * 3 * NPTS;
    if (t == 0) {
        int ci = cidx[b * NC + s];
        float cx = cb[ci], cy = cb[NPTS + ci], cz = cb[2 * NPTS + ci];
        s_c[0] = cx; s_c[1] = cy; s_c[2] = cz;
        s_cn = __fadd_rn(__fadd_rn(__fmul_rn(cx, cx), __fmul_rn(cy, cy)),
                         __fmul_rn(cz, cz));
    }
    __syncthreads();
    const float cx = s_c[0], cy = s_c[1], cz = s_c[2], cn = s_cn;
    const int base = t * 32;
    int cnt = 0;
    unsigned msk = 0;
    for (int j = 0; j < 32; ++j) {
        int p = base + j;
        float x = cb[p], y = cb[NPTS + p], z = cb[2 * NPTS + p];
        float pn = __fadd_rn(__fadd_rn(__fmul_rn(x, x), __fmul_rn(y, y)), __fmul_rn(z, z));
        float cp = __fadd_rn(__fadd_rn(__fmul_rn(cx, x), __fmul_rn(cy, y)), __fmul_rn(cz, z));
        float d2 = __fsub_rn(__fadd_rn(cn, pn), __fmul_rn(2.0f, cp));
        if (d2 < R2) { ++cnt; msk |= 1u << j; }
    }
    const int lane = t & 63, wid = t >> 6;
    int incl = cnt;
    for (int o = 1; o < 64; o <<= 1) {
        int v = __shfl_up(incl, o);
        if (lane >= o) incl += v;
    }
    if (lane == 63) s_pref[wid] = incl;
    __syncthreads();
    int ex = incl - cnt;
    for (int w = 0; w < wid; ++w) ex += s_pref[w];
    if (t == 255) s_pref[8] = ex + cnt;
    if (ex < KNN && cnt > 0) {
        int slot = ex;
        unsigned mm = msk;
        while (mm && slot < KNN) {
            int j = __builtin_ctz(mm);
            mm &= mm - 1;
            s_idx[slot] = base + j;
            ++slot;
        }
    }
    __syncthreads();
    const int total = s_pref[8];
    if (t < KNN) {
        int v = (total == 0) ? 0 : ((t < total) ? s_idx[t] : s_idx[0]);
        nidx[(b * NC + s) * KNN + t] = v;
    }
    if (t < 3) centers[(b * NC + s) * 3 + t] = s_c[t];
}

// =====================================================================
// Layer 1: block = 64 cols x 4 out-chunks of 16. Gather staged in LDS
// xs[68][64] fp32; per-thread state is only acc[16] (no spill).
// =====================================================================
__global__ __launch_bounds__(256) void l1_kernel(const float* __restrict__ xall,
                                                 const int* __restrict__ nidx,
                                                 const float* __restrict__ centers,
                                                 const float* __restrict__ wt,
                                                 const float* __restrict__ b0,
                                                 float* __restrict__ Y,
                                                 float* __restrict__ statsPL)
{
    __shared__ float sw[67 * 64 + 64];
    __shared__ float xs[68 * 64];
    __shared__ float s_sum[8], s_sq[8];
    const int b = blockIdx.y, t = threadIdx.x;
    const int col = t & 63, q = t >> 6;
    const int n = blockIdx.x * 64 + col;
    for (int i = t; i < 67 * 64; i += 256) sw[i] = wt[i];
    if (t < 64) sw[67 * 64 + t] = b0[t];
    if (t < 8) { s_sum[t] = 0.f; s_sq[t] = 0.f; }
    const int s = n >> 5, k = n & 31;
    const int p = nidx[(b * NC + s) * KNN + k];
    const float4* xp4 = (const float4*)(xall + (size_t)(b * NPTS + p) * 68);
    const float* cc = centers + (size_t)(b * NC + s) * 3;
#pragma unroll
    for (int r = 0; r < 4; ++r) {
        float4 v = xp4[q * 4 + r];
        int ch = (q * 4 + r) * 4;
        if (ch == 0) { v.x -= cc[0]; v.y -= cc[1]; v.z -= cc[2]; }
        xs[(ch + 0) * 64 + col] = v.x;
        xs[(ch + 1) * 64 + col] = v.y;
        xs[(ch + 2) * 64 + col] = v.z;
        xs[(ch + 3) * 64 + col] = v.w;
    }
    if (q == 3) {
        float4 v = xp4[16];
        xs[64 * 64 + col] = v.x;
        xs[65 * 64 + col] = v.y;
        xs[66 * 64 + col] = v.z;
        xs[67 * 64 + col] = v.w;
    }
    __syncthreads();
    float acc[16];
#pragma unroll
    for (int o = 0; o < 16; ++o) acc[o] = sw[67 * 64 + q * 16 + o];
    for (int i = 0; i < 67; ++i) {
        float xv = xs[i * 64 + col];
        const float* wr = sw + i * 64 + q * 16;
#pragma unroll
        for (int o = 0; o < 16; ++o) acc[o] = fmaf(wr[o], xv, acc[o]);
    }
    float* yb = Y + (size_t)b * 64 * NSCOL + n;
#pragma unroll
    for (int o = 0; o < 16; ++o) yb[(size_t)(q * 16 + o) * NSCOL] = acc[o];
#pragma unroll
    for (int g = 0; g < 2; ++g) {
        float sv = 0.f, sq = 0.f;
#pragma unroll
        for (int j = 0; j < 8; ++j) { float vv = acc[g * 8 + j]; sv += vv; sq = fmaf(vv, vv, sq); }
#pragma unroll
        for (int o = 32; o > 0; o >>= 1) { sv += __shfl_xor(sv, o); sq += __shfl_xor(sq, o); }
        if ((t & 63) == 0) { atomicAdd(&s_sum[q * 2 + g], sv); atomicAdd(&s_sq[q * 2 + g], sq); }
    }
    __syncthreads();
    if (t < 16) {
        const int bin = blockIdx.x & (SBINS - 1);
        const int g = t >> 1, kk = t & 1;
        atomicAdd(&statsPL[bin * 128 + (b * 8 + g) * 2 + kk], kk ? s_sq[g] : s_sum[g]);
    }
}

// =====================================================================
// Layer 2: in-place, block = 64 cols x 4 out-chunks of 16. Inlined
// stats reduction: t<16 sums the 32 partial bins of this batch's 16
// stat values (L2-hot, 512 loads/block) -- replaces the reduce_stats
// launch; kernel boundary after l1 still guarantees partials complete.
// =====================================================================
__global__ __launch_bounds__(256) void l2_kernel(const float* __restrict__ wt1,
                                                 const float* __restrict__ b1,
                                                 const float* __restrict__ g0,
                                                 const float* __restrict__ be0,
                                                 const float* __restrict__ statsPL_in,
                                                 float* __restrict__ statsPL,
                                                 float* __restrict__ Y)
{
    __shared__ float sw[64 * 64 + 64];
    __shared__ float xs[64 * 64];
    __shared__ float sA[64], sB[64];
    __shared__ float sF[16];
    __shared__ float s_sum[8], s_sq[8];
    const int b = blockIdx.y, t = threadIdx.x;
    const int col = t & 63, q = t >> 6;
    const int n = blockIdx.x * 64 + col;
    for (int i = t; i < 64 * 64; i += 256) sw[i] = wt1[i];
    if (t < 16) {
        float sv = 0.f;
#pragma unroll
        for (int bin = 0; bin < SBINS; ++bin) sv += statsPL_in[bin * 128 + b * 16 + t];
        sF[t] = sv;
    }
    if (t < 64) sw[64 * 64 + t] = b1[t];
    if (t < 8) { s_sum[t] = 0.f; s_sq[t] = 0.f; }
    __syncthreads();                                  // sF ready
    if (t < 64) {
        const int g = t >> 3;
        const float inv = 1.0f / (8.0f * NSCOL);
        float mu = sF[g * 2 + 0] * inv;
        float var = sF[g * 2 + 1] * inv - mu * mu;
        float A = (1.0f / sqrtf(var + GN_EPS)) * g0[t];
        sA[t] = A; sB[t] = be0[t] - mu * A;
    }
    __syncthreads();                                  // sA/sB + sw ready
    float* yb = Y + (size_t)b * 64 * NSCOL + n;
#pragma unroll
    for (int r = 0; r < 16; ++r) {
        int i = q * 16 + r;
        float raw = yb[(size_t)i * NSCOL];
        float v = fmaf(raw, sA[i], sB[i]);
        xs[i * 64 + col] = v * __builtin_amdgcn_rcpf(1.0f + __expf(-v));
    }
    __syncthreads();
    float acc[16];
#pragma unroll
    for (int o = 0; o < 16; ++o) acc[o] = sw[64 * 64 + q * 16 + o];
    for (int i = 0; i < 64; ++i) {
        float xv = xs[i * 64 + col];
        const float* wr = sw + i * 64 + q * 16;
#pragma unroll
        for (int o = 0; o < 16; ++o) acc[o] = fmaf(wr[o], xv, acc[o]);
    }
#pragma unroll
    for (int o = 0; o < 16; ++o) yb[(size_t)(q * 16 + o) * NSCOL] = acc[o];
#pragma unroll
    for (int g = 0; g < 2; ++g) {
        float sv = 0.f, sq = 0.f;
#pragma unroll
        for (int j = 0; j < 8; ++j) { float vv = acc[g * 8 + j]; sv += vv; sq = fmaf(vv, vv, sq); }
#pragma unroll
        for (int o = 32; o > 0; o >>= 1) { sv += __shfl_xor(sv, o); sq += __shfl_xor(sq, o); }
        if ((t & 63) == 0) { atomicAdd(&s_sum[q * 2 + g], sv); atomicAdd(&s_sq[q * 2 + g], sq); }
    }
    __syncthreads();
    if (t < 16) {
        const int bin = blockIdx.x & (SBINS - 1);
        const int g = t >> 1, kk = t & 1;
        atomicAdd(&statsPL[bin * 128 + (b * 8 + g) * 2 + kk], kk ? s_sq[g] : s_sum[g]);
    }
}

// =====================================================================
// Layer 3: in-place, block = 64 cols x 4 out-chunks of 32 (128 out).
// Inlined stats reduction (as l2). Output bf16 pair-packed.
// =====================================================================
__global__ __launch_bounds__(256) void l3_kernel(const float* __restrict__ wt2,
                                                 const float* __restrict__ b2,
                                                 const float* __restrict__ g1,
                                                 const float* __restrict__ be1,
                                                 const float* __restrict__ statsPL_in,
                                                 float* __restrict__ statsPL,
                                                 float* __restrict__ Y)
{
    __shared__ float sw[64 * 128 + 128];
    __shared__ float xs[64 * 64];
    __shared__ float sA[64], sB[64];
    __shared__ float sF[16];
    __shared__ float s_sum[8], s_sq[8];
    const int b = blockIdx.y, t = threadIdx.x;
    const int col = t & 63, q = t >> 6;
    const int n = blockIdx.x * 64 + col;
    for (int i = t; i < 64 * 128; i += 256) sw[i] = wt2[i];
    if (t < 16) {
        float sv = 0.f;
#pragma unroll
        for (int bin = 0; bin < SBINS; ++bin) sv += statsPL_in[bin * 128 + b * 16 + t];
        sF[t] = sv;
    }
    if (t < 128) sw[64 * 128 + t] = b2[t];
    if (t < 8) { s_sum[t] = 0.f; s_sq[t] = 0.f; }
    __syncthreads();                                  // sF ready
    if (t < 64) {
        const int g = t >> 3;
        const float inv = 1.0f / (8.0f * NSCOL);
        float mu = sF[g * 2 + 0] * inv;
        float var = sF[g * 2 + 1] * inv - mu * mu;
        float A = (1.0f / sqrtf(var + GN_EPS)) * g1[t];
        sA[t] = A; sB[t] = be1[t] - mu * A;
    }
    __syncthreads();                                  // sA/sB + sw ready
    float* yb = Y + (size_t)b * 64 * NSCOL + n;
#pragma unroll
    for (int r = 0; r < 16; ++r) {
        int i = q * 16 + r;
        float raw = yb[(size_t)i * NSCOL];
        float v = fmaf(raw, sA[i], sB[i]);
        xs[i * 64 + col] = v * __builtin_amdgcn_rcpf(1.0f + __expf(-v));
    }
    __syncthreads();
    float acc[32];
#pragma unroll
    for (int o = 0; o < 32; ++o) acc[o] = sw[64 * 128 + q * 32 + o];
    for (int i = 0; i < 64; ++i) {
        float xv = xs[i * 64 + col];
        const float* wr = sw + i * 128 + q * 32;
#pragma unroll
        for (int o = 0; o < 32; ++o) acc[o] = fmaf(wr[o], xv, acc[o]);
    }
#pragma unroll
    for (int g = 0; g < 2; ++g) {
        float sv = 0.f, sq = 0.f;
#pragma unroll
        for (int j = 0; j < 16; ++j) { float vv = acc[g * 16 + j]; sv += vv; sq = fmaf(vv, vv, sq); }
#pragma unroll
        for (int o = 32; o > 0; o >>= 1) { sv += __shfl_xor(sv, o); sq += __shfl_xor(sq, o); }
        if ((t & 63) == 0) { atomicAdd(&s_sum[q * 2 + g], sv); atomicAdd(&s_sq[q * 2 + g], sq); }
    }
    unsigned* yu = (unsigned*)yb;
#pragma unroll
    for (int j = 0; j < 16; ++j) {
        unsigned u = f2bf(acc[2 * j]) | (f2bf(acc[2 * j + 1]) << 16);
        yu[(size_t)(q * 16 + j) * NSCOL] = u;
    }
    __syncthreads();
    if (t < 16) {
        const int bin = blockIdx.x & (SBINS - 1);
        const int g = t >> 1, kk = t & 1;
        atomicAdd(&statsPL[bin * 128 + (b * 8 + g) * 2 + kk], kk ? s_sq[g] : s_sum[g]);
    }
}

// =====================================================================
// Finalize: GN3 + SiLU + max over K. Thread per (b, channel-PAIR, s).
// Inlined stats reduction: each block spans 256 s-values of ONE (b,cp)
// pair -> one group -> 2 stat values; t<2 sums the 32 partial bins.
// =====================================================================
__global__ __launch_bounds__(256) void fin_kernel(const unsigned* __restrict__ Yu,
                                                  const float* __restrict__ g2,
                                                  const float* __restrict__ be2,
                                                  const float* __restrict__ statsPL_in,
                                                  float* __restrict__ out)
{
    const int t = threadIdx.x;
    const int tid = blockIdx.x * 256 + t;
    const int s = tid & (NC - 1);
    const int cp = (tid >> 11) & 63;
    const int b = tid >> 17;
    const int g = cp >> 3;
    __shared__ float s_st[2];
    if (t < 2) {
        float sv = 0.f;
#pragma unroll
        for (int bin = 0; bin < SBINS; ++bin) sv += statsPL_in[bin * 128 + (b * 8 + g) * 2 + t];
        s_st[t] = sv;
    }
    __syncthreads();
    const float inv = 1.0f / (16.0f * NSCOL);
    float mu = s_st[0] * inv;
    float var = s_st[1] * inv - mu * mu;
    float rs = 1.0f / sqrtf(var + GN_EPS);
    const int c0 = cp * 2, c1 = c0 + 1;
    float A0 = rs * g2[c0], B0 = be2[c0] - mu * A0;
    float A1 = rs * g2[c1], B1 = be2[c1] - mu * A1;
    const unsigned* yb = Yu + (size_t)(b * 64 + cp) * NSCOL + s * KNN;
    float m0 = -INFINITY, m1 = -INFINITY;
#pragma unroll
    for (int qq = 0; qq < 8; ++qq) {
        uint4 v = ((const uint4*)yb)[qq];
        unsigned uu[4] = {v.x, v.y, v.z, v.w};
#pragma unroll
        for (int r = 0; r < 4; ++r) {
            float f0 = __uint_as_float(uu[r] << 16);
            float f1 = __uint_as_float(uu[r] & 0xffff0000u);
            float v0 = fmaf(f0, A0, B0);
            v0 = v0 * __builtin_amdgcn_rcpf(1.0f + __expf(-v0));
            m0 = fmaxf(m0, v0);
            float v1 = fmaf(f1, A1, B1);
            v1 = v1 * __builtin_amdgcn_rcpf(1.0f + __expf(-v1));
            m1 = fmaxf(m1, v1);
        }
    }
    out[(size_t)(b * 128 + c0) * NC + s] = m0;
    out[(size_t)(b * 128 + c1) * NC + s] = m1;
}

// =====================================================================
extern "C" void kernel_launch(void* const* d_in, const int* in_sizes, int n_in,
                              void* d_out, int out_size, void* d_ws, size_t ws_size,
                              hipStream_t stream)
{
    if (ws_size < WS_NEEDED) return;

    const float* coords = (const float*)d_in[0];
    const float* feats  = (const float*)d_in[1];
    const float* w0  = (const float*)d_in[2];
    const float* b0  = (const float*)d_in[3];
    const float* g0  = (const float*)d_in[4];
    const float* be0 = (const float*)d_in[5];
    const float* w1  = (const float*)d_in[6];
    const float* b1  = (const float*)d_in[7];
    const float* g1  = (const float*)d_in[8];
    const float* be1 = (const float*)d_in[9];
    const float* w2  = (const float*)d_in[10];
    const float* b2  = (const float*)d_in[11];
    const float* g2  = (const float*)d_in[12];
    const float* be2 = (const float*)d_in[13];
    float* out = (float*)d_out;

    char* ws = (char*)d_ws;
    int*   cidx    = (int*)(ws + OFF_CIDX);
    int*   nidx    = (int*)(ws + OFF_NIDX);
    float* centers = (float*)(ws + OFF_CENT);
    float* statsP  = (float*)(ws + OFF_STATSP);   // [3][SBINS][128]
    float* wt      = (float*)(ws + OFF_WT);
    float* xall    = (float*)(ws + OFF_XALL);
    float* Ybuf    = (float*)(ws + OFF_Y);

    build_xall<<<(BATCH * NPTS) / 256, 256, 0, stream>>>(coords, feats,
                                                         w0, w1, w2, statsP, wt, xall);
    // dynamic LDS: 3*NPTS floats (coords) + 16 u64 packs (2x8 dbuf)
    fps_kernel<<<BATCH, 512, 3 * NPTS * 4 + 128, stream>>>(coords, cidx);
    bq_kernel<<<dim3(NC, BATCH), 256, 0, stream>>>(coords, cidx, nidx, centers);

    const dim3 lgrid(NSCOL / 64, BATCH);
    l1_kernel<<<lgrid, 256, 0, stream>>>(xall, nidx, centers, wt, b0, Ybuf, statsP);
    l2_kernel<<<lgrid, 256, 0, stream>>>(wt + 4288, b1, g0, be0,
                                         statsP, statsP + SBINS * 128, Ybuf);
    l3_kernel<<<lgrid, 256, 0, stream>>>(wt + 8384, b2, g1, be1,
                                         statsP + SBINS * 128, statsP + 2 * SBINS * 128, Ybuf);
    fin_kernel<<<(BATCH * 64 * NC) / 256, 256, 0, stream>>>(
        (const unsigned*)Ybuf, g2, be2, statsP + 2 * SBINS * 128, out);
    (void)in_sizes; (void)n_in; (void)out_size;
}